// Round 2
// baseline (856.576 us; speedup 1.0000x reference)
//
#include <hip/hip_runtime.h>

typedef unsigned short u16t;
typedef __bf16 bf16x8 __attribute__((ext_vector_type(8)));
typedef float f32x4 __attribute__((ext_vector_type(4)));

#define NB 4
#define NS 2048
#define ND 1024
#define NH 16
#define NDK 64
#define NEGINF -1.0e9f
// softmax runs in exp2 domain: SCALE2 = 0.125 * log2(e)
#define SCALE2 0.18033688011112042f

// padded LDS row stride for gemm (32-wide tiles): 40 elem = 80B, 5 granules,
// coprime with 8 -> conflict-free frag reads. probs_mean 64-wide tiles: 72.
#define LAB 40
#define LKV 72

__device__ __forceinline__ float fexp2(float x) { return __builtin_amdgcn_exp2f(x); }

// DPP rotate within 16-lane rows (lane bits 0..3 == the softmax row groups)
#define ROR16(x, n) __builtin_bit_cast(float, __builtin_amdgcn_update_dpp(     \
    __builtin_bit_cast(int, (x)), __builtin_bit_cast(int, (x)),                \
    0x120 + (n), 0xF, 0xF, false))

__device__ __forceinline__ u16t f2bf(float f) {
  unsigned u = __builtin_bit_cast(unsigned, f);
  u += 0x7fffu + ((u >> 16) & 1u);   // RNE
  return (u16t)(u >> 16);
}

// XOR-swizzle index for [64][64] u16 tiles: rotates 16B granules within each
// 8-row stripe -> conflict-free b128 reads at 128B row stride (no padding).
__device__ __forceinline__ int swz(int row, int col) {
  return row * 64 + (col ^ ((row & 7) << 3));
}

// register staging helpers (raw loads now, convert at LDS-store time)
template<typename TA> struct Stg;
template<> struct Stg<float> {
  f32x4 lo, hi;
  __device__ __forceinline__ void ld(const float* p) {
    lo = *(const f32x4*)p; hi = *(const f32x4*)(p + 4);
  }
  __device__ __forceinline__ bf16x8 get() const {
    bf16x8 r;
    r[0] = (__bf16)lo[0]; r[1] = (__bf16)lo[1]; r[2] = (__bf16)lo[2]; r[3] = (__bf16)lo[3];
    r[4] = (__bf16)hi[0]; r[5] = (__bf16)hi[1]; r[6] = (__bf16)hi[2]; r[7] = (__bf16)hi[3];
    return r;
  }
};
template<> struct Stg<u16t> {
  bf16x8 v;
  __device__ __forceinline__ void ld(const u16t* p) { v = *(const bf16x8*)p; }
  __device__ __forceinline__ bf16x8 get() const { return v; }
};

// ---------------------------------------------------------------------------
// NT GEMM: C[M,N] = A[M,K] * B[N,K]^T ; M=8192, N=K=1024, bf16 MFMA, fp32 acc.
// MODE 0: C fp32 row-major [M,N] + bias[col]   (output projection -> d_out)
// MODE 1: C bf16 scatter to [B,H,S,dk]         (Q/K projections -> ws)
// MODE 2: C bf16 scatter to [B,H,dk,S]         (V projection, transposed -> ws)
// Software-pipelined: next K-step's global loads issue before the MFMA block.
// ---------------------------------------------------------------------------
template<typename TA, int MODE>
__global__ __launch_bounds__(256, 2)
void gemm_nt(const TA* __restrict__ A, const float* __restrict__ Bm,
             void* __restrict__ Cv, const float* __restrict__ bias)
{
  const int K = 1024;
  __shared__ __attribute__((aligned(16))) u16t At[128 * LAB];
  __shared__ __attribute__((aligned(16))) u16t Bt[128 * LAB];

  const int tid  = threadIdx.x;
  const int w    = tid >> 6;
  const int lane = tid & 63;
  const int quad = lane >> 4;
  const int l16  = lane & 15;
  const int wm   = w >> 1, wn = w & 1;
  const int m0   = blockIdx.x * 128;
  const int n0   = blockIdx.y * 128;

  const f32x4 fz = {0.f, 0.f, 0.f, 0.f};
  f32x4 acc[4][4];
#pragma unroll
  for (int i = 0; i < 4; i++)
#pragma unroll
    for (int j = 0; j < 4; j++) acc[i][j] = fz;

  // staging chunk map: chunk c (0..511) -> row c>>2 (0..127), colgrp (c&3)*8
  const int r0 = tid >> 2, cg = (tid & 3) * 8;
  const int r1 = r0 + 64;

  Stg<TA> sa0, sa1; Stg<float> sb0, sb1;
  sa0.ld(A  + (long)(m0 + r0) * K + cg);
  sa1.ld(A  + (long)(m0 + r1) * K + cg);
  sb0.ld(Bm + (long)(n0 + r0) * K + cg);
  sb1.ld(Bm + (long)(n0 + r1) * K + cg);

  for (int k0 = 0; k0 < K; k0 += 32) {
    __syncthreads();
    *(bf16x8*)&At[r0 * LAB + cg] = sa0.get();
    *(bf16x8*)&At[r1 * LAB + cg] = sa1.get();
    *(bf16x8*)&Bt[r0 * LAB + cg] = sb0.get();
    *(bf16x8*)&Bt[r1 * LAB + cg] = sb1.get();
    __syncthreads();
    if (k0 + 32 < K) {
      sa0.ld(A  + (long)(m0 + r0) * K + k0 + 32 + cg);
      sa1.ld(A  + (long)(m0 + r1) * K + k0 + 32 + cg);
      sb0.ld(Bm + (long)(n0 + r0) * K + k0 + 32 + cg);
      sb1.ld(Bm + (long)(n0 + r1) * K + k0 + 32 + cg);
    }

    bf16x8 af[4], bfv[4];
#pragma unroll
    for (int i = 0; i < 4; i++)
      af[i] = *(const bf16x8*)&At[(wm * 64 + i * 16 + l16) * LAB + quad * 8];
#pragma unroll
    for (int j = 0; j < 4; j++)
      bfv[j] = *(const bf16x8*)&Bt[(wn * 64 + j * 16 + l16) * LAB + quad * 8];
#pragma unroll
    for (int i = 0; i < 4; i++)
#pragma unroll
      for (int j = 0; j < 4; j++)
        acc[i][j] = __builtin_amdgcn_mfma_f32_16x16x32_bf16(af[i], bfv[j], acc[i][j], 0, 0, 0);
  }

#pragma unroll
  for (int i = 0; i < 4; i++) {
    const int rbase = m0 + wm * 64 + i * 16 + quad * 4;
#pragma unroll
    for (int j = 0; j < 4; j++) {
      const int col = n0 + wn * 64 + j * 16 + l16;
      float bv = 0.f;
      if (MODE == 0) bv = bias[col];
#pragma unroll
      for (int r = 0; r < 4; r++) {
        const int row = rbase + r;
        float v = acc[i][j][r];
        if (MODE == 0) {
          ((float*)Cv)[(long)row * ND + col] = v + bv;
        } else if (MODE == 1) {
          int b = row >> 11, s = row & 2047, h = col >> 6, d = col & 63;
          ((u16t*)Cv)[(((long)(b * NH + h)) * NS + s) * NDK + d] = f2bf(v);
        } else {
          int b = row >> 11, s = row & 2047, h = col >> 6, d = col & 63;
          ((u16t*)Cv)[(((long)(b * NH + h)) * NDK + d) * NS + s] = f2bf(v);
        }
      }
    }
  }
}

// ---------------------------------------------------------------------------
// Flash attention pass: per (b,h, 128-row q tile). 4 waves x 32 q rows.
// exp2-domain online softmax; DPP rotate-reduce (no LDS shuffles); exact
// skip-rescale when no row max grows; swizzled [64][64] LDS tiles (40960 B
// total -> 4 blocks/CU); software-pipelined K/V staging.
// ---------------------------------------------------------------------------
__global__ __launch_bounds__(256, 4)
void flash_ctx(const u16t* __restrict__ Qw, const u16t* __restrict__ Kw,
               const u16t* __restrict__ VTw, const int* __restrict__ mask,
               u16t* __restrict__ ctx, float* __restrict__ mo, float* __restrict__ lo)
{
  __shared__ __attribute__((aligned(16))) u16t Kt[64 * 64];
  __shared__ __attribute__((aligned(16))) u16t Vt[64 * 64];
  __shared__ __attribute__((aligned(16))) u16t Pt[4 * 32 * 64];
  __shared__ float biasl[NS];

  const int tid  = threadIdx.x;
  const int w    = tid >> 6;
  const int lane = tid & 63;
  const int quad = lane >> 4;
  const int l16  = lane & 15;
  const int bh   = blockIdx.y;        // b*16 + h
  const int b    = bh >> 4;
  const int h    = bh & 15;
  const int qw   = blockIdx.x * 128 + w * 32;
  const int pbase = w * 2048;

  for (int i = tid; i < NS; i += 256)
    biasl[i] = mask[b * NS + i] ? 0.f : NEGINF;

  // preload this wave's Q fragments (32 rows x 64 d) into registers
  bf16x8 qf[2][2];
#pragma unroll
  for (int g = 0; g < 2; g++)
#pragma unroll
    for (int kk = 0; kk < 2; kk++)
      qf[g][kk] = *(const bf16x8*)(Qw + ((long)bh * NS + qw + g * 16 + l16) * NDK + kk * 32 + quad * 8);

  const f32x4 fz = {0.f, 0.f, 0.f, 0.f};
  const f32x4 fm = {NEGINF, NEGINF, NEGINF, NEGINF};
  f32x4 cacc[2][4];
#pragma unroll
  for (int g = 0; g < 2; g++)
#pragma unroll
    for (int d = 0; d < 4; d++) cacc[g][d] = fz;
  f32x4 mrun[2] = {fm, fm};
  f32x4 lrun[2] = {fz, fz};

  // staging chunk map: chunk c (0..511) -> row c>>3 (0..63), colgrp (c&7)*8
  const int kr0 = tid >> 3, kc0 = (tid & 7) * 8;
  const int kr1 = kr0 + 32;
  const long kbase = (long)bh * NS;
  const long vbase = (long)bh * NDK;

  bf16x8 k0v = *(const bf16x8*)(Kw  + (kbase + kr0) * NDK + kc0);
  bf16x8 k1v = *(const bf16x8*)(Kw  + (kbase + kr1) * NDK + kc0);
  bf16x8 v0v = *(const bf16x8*)(VTw + (vbase + kr0) * NS + kc0);
  bf16x8 v1v = *(const bf16x8*)(VTw + (vbase + kr1) * NS + kc0);

  for (int kb = 0; kb < NS; kb += 64) {
    __syncthreads();
    *(bf16x8*)&Kt[swz(kr0, kc0)] = k0v;
    *(bf16x8*)&Kt[swz(kr1, kc0)] = k1v;
    *(bf16x8*)&Vt[swz(kr0, kc0)] = v0v;
    *(bf16x8*)&Vt[swz(kr1, kc0)] = v1v;
    __syncthreads();
    if (kb + 64 < NS) {   // prefetch next tile; latency hides under compute
      k0v = *(const bf16x8*)(Kw  + (kbase + kb + 64 + kr0) * NDK + kc0);
      k1v = *(const bf16x8*)(Kw  + (kbase + kb + 64 + kr1) * NDK + kc0);
      v0v = *(const bf16x8*)(VTw + (vbase + kr0) * NS + kb + 64 + kc0);
      v1v = *(const bf16x8*)(VTw + (vbase + kr1) * NS + kb + 64 + kc0);
    }

    // S = Q K^T (rows: q, cols: key)
    f32x4 s[2][4];
#pragma unroll
    for (int g = 0; g < 2; g++)
#pragma unroll
      for (int c = 0; c < 4; c++) {
        f32x4 a = fz;
#pragma unroll
        for (int kk = 0; kk < 2; kk++) {
          bf16x8 kf = *(const bf16x8*)&Kt[swz(c * 16 + l16, kk * 32 + quad * 8)];
          a = __builtin_amdgcn_mfma_f32_16x16x32_bf16(qf[g][kk], kf, a, 0, 0, 0);
        }
        s[g][c] = a;
      }

    float bias_c[4];
#pragma unroll
    for (int c = 0; c < 4; c++) bias_c[c] = biasl[kb + c * 16 + l16];

#pragma unroll
    for (int g = 0; g < 2; g++) {
#pragma unroll
      for (int c = 0; c < 4; c++)
#pragma unroll
        for (int r = 0; r < 4; r++)
          s[g][c][r] = s[g][c][r] * SCALE2 + bias_c[c];

      // row max: fold 4 col-frags, then DPP rotate-reduce over the 16 lanes
      f32x4 mx = s[g][0];
#pragma unroll
      for (int c = 1; c < 4; c++)
#pragma unroll
        for (int r = 0; r < 4; r++) mx[r] = fmaxf(mx[r], s[g][c][r]);
#pragma unroll
      for (int r = 0; r < 4; r++) {
        float x = mx[r];
        x = fmaxf(x, ROR16(x, 1));
        x = fmaxf(x, ROR16(x, 2));
        x = fmaxf(x, ROR16(x, 4));
        x = fmaxf(x, ROR16(x, 8));
        mx[r] = x;
      }

      // exact skip-rescale: only rescale if some row's max grew (alpha != 1)
      bool grow = (mx[0] > mrun[g][0]) | (mx[1] > mrun[g][1]) |
                  (mx[2] > mrun[g][2]) | (mx[3] > mrun[g][3]);
      if (__any((int)grow)) {
#pragma unroll
        for (int r = 0; r < 4; r++) {
          float mnew = fmaxf(mrun[g][r], mx[r]);
          float al = fexp2(mrun[g][r] - mnew);
          mrun[g][r] = mnew;
          lrun[g][r] *= al;
#pragma unroll
          for (int d = 0; d < 4; d++) cacc[g][d][r] *= al;
        }
      }

#pragma unroll
      for (int c = 0; c < 4; c++)
#pragma unroll
        for (int r = 0; r < 4; r++) s[g][c][r] = fexp2(s[g][c][r] - mrun[g][r]);

      f32x4 sm = fz;
#pragma unroll
      for (int c = 0; c < 4; c++)
#pragma unroll
        for (int r = 0; r < 4; r++) sm[r] += s[g][c][r];
#pragma unroll
      for (int r = 0; r < 4; r++) {
        float x = sm[r];
        x += ROR16(x, 1);
        x += ROR16(x, 2);
        x += ROR16(x, 4);
        x += ROR16(x, 8);
        lrun[g][r] += x;
      }

      // P -> LDS (A-operand layout: [q][key] row-major, swizzled)
#pragma unroll
      for (int c = 0; c < 4; c++)
#pragma unroll
        for (int r = 0; r < 4; r++)
          Pt[pbase + swz(g * 16 + quad * 4 + r, c * 16 + l16)] = f2bf(s[g][c][r]);
    }

    // context += P * V  (Pt region is per-wave; same-wave DS ops are in order)
#pragma unroll
    for (int g = 0; g < 2; g++)
#pragma unroll
      for (int d = 0; d < 4; d++)
#pragma unroll
        for (int kk = 0; kk < 2; kk++) {
          bf16x8 pf = *(const bf16x8*)&Pt[pbase + swz(g * 16 + l16, kk * 32 + quad * 8)];
          bf16x8 vf = *(const bf16x8*)&Vt[swz(d * 16 + l16, kk * 32 + quad * 8)];
          cacc[g][d] = __builtin_amdgcn_mfma_f32_16x16x32_bf16(pf, vf, cacc[g][d], 0, 0, 0);
        }
  }

  // epilogue: normalize, write context and (m,l)
#pragma unroll
  for (int g = 0; g < 2; g++) {
    f32x4 rinv;
#pragma unroll
    for (int r = 0; r < 4; r++) rinv[r] = 1.f / lrun[g][r];
#pragma unroll
    for (int d = 0; d < 4; d++)
#pragma unroll
      for (int r = 0; r < 4; r++) {
        int qg = qw + g * 16 + quad * 4 + r;
        int e  = h * NDK + d * 16 + l16;
        ctx[((long)(b * NS + qg)) * ND + e] = f2bf(cacc[g][d][r] * rinv[r]);
      }
    if (l16 == 0) {
#pragma unroll
      for (int r = 0; r < 4; r++) {
        int qg = qw + g * 16 + quad * 4 + r;
        mo[(long)bh * NS + qg] = mrun[g][r];
        lo[(long)bh * NS + qg] = lrun[g][r];
      }
    }
  }
}

// ---------------------------------------------------------------------------
// probs_mean: per (b, 128x128 score tile), loop all 16 heads recomputing
// S = Q K^T, p = exp2(s*SCALE2 + maskbias - m)/l, accumulate mean, fp32 out.
// Software-pipelined head staging.
// ---------------------------------------------------------------------------
__global__ __launch_bounds__(256, 2)
void probs_mean(const u16t* __restrict__ Qw, const u16t* __restrict__ Kw,
                const int* __restrict__ mask, const float* __restrict__ mo,
                const float* __restrict__ lo, float* __restrict__ outp)
{
  __shared__ __attribute__((aligned(16))) u16t Qt[128 * LKV];
  __shared__ __attribute__((aligned(16))) u16t Kt2[128 * LKV];
  __shared__ float ml[NH * 128];
  __shared__ float li[NH * 128];
  __shared__ float biasl[128];

  const int tid  = threadIdx.x;
  const int w    = tid >> 6;
  const int lane = tid & 63;
  const int quad = lane >> 4;
  const int l16  = lane & 15;
  const int wm   = w >> 1, wn = w & 1;
  const int b  = blockIdx.z;
  const int q0 = blockIdx.y * 128;
  const int k0 = blockIdx.x * 128;

  for (int i = tid; i < NH * 128; i += 256) {
    int hh = i >> 7, r = i & 127;
    ml[i] = mo[((long)(b * NH + hh)) * NS + q0 + r];
    li[i] = 1.f / lo[((long)(b * NH + hh)) * NS + q0 + r];
  }
  for (int i = tid; i < 128; i += 256)
    biasl[i] = mask[b * NS + k0 + i] ? 0.f : NEGINF;

  const f32x4 fz = {0.f, 0.f, 0.f, 0.f};
  f32x4 acc[4][4];
#pragma unroll
  for (int i = 0; i < 4; i++)
#pragma unroll
    for (int j = 0; j < 4; j++) acc[i][j] = fz;

  bf16x8 qv[4], kv[4];
#pragma unroll
  for (int rr = 0; rr < 4; rr++) {
    int idx = rr * 256 + tid;
    int row = idx >> 3, off = (idx & 7) * 8;
    qv[rr] = *(const bf16x8*)(Qw + ((long)(b * NH) * NS + q0 + row) * NDK + off);
    kv[rr] = *(const bf16x8*)(Kw + ((long)(b * NH) * NS + k0 + row) * NDK + off);
  }

  for (int hh = 0; hh < NH; hh++) {
    __syncthreads();
#pragma unroll
    for (int rr = 0; rr < 4; rr++) {
      int idx = rr * 256 + tid;
      int row = idx >> 3, off = (idx & 7) * 8;
      *(bf16x8*)&Qt[row * LKV + off]  = qv[rr];
      *(bf16x8*)&Kt2[row * LKV + off] = kv[rr];
    }
    __syncthreads();
    if (hh + 1 < NH) {
#pragma unroll
      for (int rr = 0; rr < 4; rr++) {
        int idx = rr * 256 + tid;
        int row = idx >> 3, off = (idx & 7) * 8;
        qv[rr] = *(const bf16x8*)(Qw + ((long)(b * NH + hh + 1) * NS + q0 + row) * NDK + off);
        kv[rr] = *(const bf16x8*)(Kw + ((long)(b * NH + hh + 1) * NS + k0 + row) * NDK + off);
      }
    }

    bf16x8 af[4][2], bfv[4][2];
#pragma unroll
    for (int i = 0; i < 4; i++)
#pragma unroll
      for (int kk = 0; kk < 2; kk++) {
        af[i][kk]  = *(const bf16x8*)&Qt[(wm * 64 + i * 16 + l16) * LKV + kk * 32 + quad * 8];
        bfv[i][kk] = *(const bf16x8*)&Kt2[(wn * 64 + i * 16 + l16) * LKV + kk * 32 + quad * 8];
      }
#pragma unroll
    for (int i = 0; i < 4; i++)
#pragma unroll
      for (int j = 0; j < 4; j++) {
        f32x4 s = fz;
#pragma unroll
        for (int kk = 0; kk < 2; kk++)
          s = __builtin_amdgcn_mfma_f32_16x16x32_bf16(af[i][kk], bfv[j][kk], s, 0, 0, 0);
        const float bias_c = biasl[wn * 64 + j * 16 + l16];
#pragma unroll
        for (int r = 0; r < 4; r++) {
          int rowb = wm * 64 + i * 16 + quad * 4 + r;
          float p = fexp2(s[r] * SCALE2 + bias_c - ml[hh * 128 + rowb]) * li[hh * 128 + rowb];
          acc[i][j][r] += p;
        }
      }
  }

#pragma unroll
  for (int i = 0; i < 4; i++)
#pragma unroll
    for (int j = 0; j < 4; j++)
#pragma unroll
      for (int r = 0; r < 4; r++) {
        int row = q0 + wm * 64 + i * 16 + quad * 4 + r;
        int col = k0 + wn * 64 + j * 16 + l16;
        outp[((long)(b * NS + row)) * NS + col] = acc[i][j][r] * (1.f / 16.f);
      }
}

// ---------------------------------------------------------------------------
extern "C" void kernel_launch(void* const* d_in, const int* in_sizes, int n_in,
                              void* d_out, int out_size, void* d_ws, size_t ws_size,
                              hipStream_t stream)
{
  (void)in_sizes; (void)n_in; (void)out_size; (void)ws_size;
  const float* query = (const float*)d_in[0];
  const float* keyt  = (const float*)d_in[1];
  const float* value = (const float*)d_in[2];
  const int*   mask  = (const int*)d_in[3];
  const float* Wq = (const float*)d_in[4];
  const float* Wk = (const float*)d_in[5];
  const float* Wv = (const float*)d_in[6];
  const float* Wo = (const float*)d_in[7];
  const float* bo = (const float*)d_in[8];

  float* out  = (float*)d_out;                     // [B,S,D] fp32
  float* outp = out + (long)NB * NS * ND;          // [B,S,S] fp32

  u16t* q_ws  = (u16t*)d_ws;                       // [B,H,S,dk] bf16
  u16t* k_ws  = q_ws + (long)NB * NH * NS * NDK;   // [B,H,S,dk] bf16
  u16t* vt_ws = k_ws + (long)NB * NH * NS * NDK;   // [B,H,dk,S] bf16
  float* m_ws = (float*)(vt_ws + (long)NB * NH * NS * NDK);
  float* l_ws = m_ws + (long)NB * NH * NS;
  // ctx scratch (bf16) lives in the outp region of d_out; it is fully
  // consumed by the output GEMM before probs_mean overwrites the region.
  u16t* ctx_ws = (u16t*)outp;

  dim3 blk(256);
  gemm_nt<float, 1><<<dim3(64, 8), blk, 0, stream>>>(query, Wq, q_ws, nullptr);
  gemm_nt<float, 1><<<dim3(64, 8), blk, 0, stream>>>(keyt,  Wk, k_ws, nullptr);
  gemm_nt<float, 2><<<dim3(64, 8), blk, 0, stream>>>(value, Wv, vt_ws, nullptr);
  flash_ctx<<<dim3(NS / 128, NB * NH), blk, 0, stream>>>(q_ws, k_ws, vt_ws, mask,
                                                         ctx_ws, m_ws, l_ws);
  gemm_nt<u16t, 0><<<dim3(64, 8), blk, 0, stream>>>(ctx_ws, Wo, out, bo);
  probs_mean<<<dim3(NS / 128, NS / 128, NB), blk, 0, stream>>>(q_ws, k_ws, mask,
                                                               m_ws, l_ws, outp);
}

// Round 3
// 662.996 us; speedup vs baseline: 1.2920x; 1.2920x over previous
//
#include <hip/hip_runtime.h>

typedef unsigned short u16t;
typedef __bf16 bf16x8 __attribute__((ext_vector_type(8)));
typedef float f32x4 __attribute__((ext_vector_type(4)));

#define NB 4
#define NS 2048
#define ND 1024
#define NH 16
#define NDK 64
#define NEGINF -1.0e9f
// softmax runs in exp2 domain: SCALE2 = 0.125 * log2(e)
#define SCALE2 0.18033688011112042f

// padded LDS row stride for gemm (32-wide tiles): 40 elem = 80B, 5 granules,
// coprime with 8 -> conflict-free frag reads.
#define LAB 40

__device__ __forceinline__ float fexp2(float x) { return __builtin_amdgcn_exp2f(x); }

// DPP rotate within 16-lane rows (lane bits 0..3 == the softmax row groups)
#define ROR16(x, n) __builtin_bit_cast(float, __builtin_amdgcn_update_dpp(     \
    __builtin_bit_cast(int, (x)), __builtin_bit_cast(int, (x)),                \
    0x120 + (n), 0xF, 0xF, false))

__device__ __forceinline__ u16t f2bf(float f) {
  unsigned u = __builtin_bit_cast(unsigned, f);
  u += 0x7fffu + ((u >> 16) & 1u);   // RNE
  return (u16t)(u >> 16);
}

// XOR-swizzle index for [*][64] u16 tiles: rotates 16B granules within each
// 8-row stripe -> conflict-free b128 reads at 128B row stride (no padding).
// Verified: R2 flash SQ_LDS_BANK_CONFLICT == 0 with this on both sides.
__device__ __forceinline__ int swz(int row, int col) {
  return row * 64 + (col ^ ((row & 7) << 3));
}

// register staging helpers (raw loads now, convert at LDS-store time)
template<typename TA> struct Stg;
template<> struct Stg<float> {
  f32x4 lo, hi;
  __device__ __forceinline__ void ld(const float* p) {
    lo = *(const f32x4*)p; hi = *(const f32x4*)(p + 4);
  }
  __device__ __forceinline__ bf16x8 get() const {
    bf16x8 r;
    r[0] = (__bf16)lo[0]; r[1] = (__bf16)lo[1]; r[2] = (__bf16)lo[2]; r[3] = (__bf16)lo[3];
    r[4] = (__bf16)hi[0]; r[5] = (__bf16)hi[1]; r[6] = (__bf16)hi[2]; r[7] = (__bf16)hi[3];
    return r;
  }
};
template<> struct Stg<u16t> {
  bf16x8 v;
  __device__ __forceinline__ void ld(const u16t* p) { v = *(const bf16x8*)p; }
  __device__ __forceinline__ bf16x8 get() const { return v; }
};

// ---------------------------------------------------------------------------
// NT GEMM: C[M,N] = A[M,K] * B[N,K]^T ; M=8192, N=K=1024, bf16 MFMA, fp32 acc.
// MODE 0: C fp32 row-major [M,N] + bias[col]   (output projection -> d_out)
// MODE 1: C bf16 scatter to [B,H,S,dk]         (Q/K projections -> ws)
// MODE 2: C bf16 scatter to [B,H,dk,S]         (V projection, transposed -> ws)
// Software-pipelined: next K-step's global loads issue before the MFMA block.
// ---------------------------------------------------------------------------
template<typename TA, int MODE>
__global__ __launch_bounds__(256, 2)
void gemm_nt(const TA* __restrict__ A, const float* __restrict__ Bm,
             void* __restrict__ Cv, const float* __restrict__ bias)
{
  const int K = 1024;
  __shared__ __attribute__((aligned(16))) u16t At[128 * LAB];
  __shared__ __attribute__((aligned(16))) u16t Bt[128 * LAB];

  const int tid  = threadIdx.x;
  const int w    = tid >> 6;
  const int lane = tid & 63;
  const int quad = lane >> 4;
  const int l16  = lane & 15;
  const int wm   = w >> 1, wn = w & 1;
  const int m0   = blockIdx.x * 128;
  const int n0   = blockIdx.y * 128;

  const f32x4 fz = {0.f, 0.f, 0.f, 0.f};
  f32x4 acc[4][4];
#pragma unroll
  for (int i = 0; i < 4; i++)
#pragma unroll
    for (int j = 0; j < 4; j++) acc[i][j] = fz;

  // staging chunk map: chunk c (0..511) -> row c>>2 (0..127), colgrp (c&3)*8
  const int r0 = tid >> 2, cg = (tid & 3) * 8;
  const int r1 = r0 + 64;

  Stg<TA> sa0, sa1; Stg<float> sb0, sb1;
  sa0.ld(A  + (long)(m0 + r0) * K + cg);
  sa1.ld(A  + (long)(m0 + r1) * K + cg);
  sb0.ld(Bm + (long)(n0 + r0) * K + cg);
  sb1.ld(Bm + (long)(n0 + r1) * K + cg);

  for (int k0 = 0; k0 < K; k0 += 32) {
    __syncthreads();
    *(bf16x8*)&At[r0 * LAB + cg] = sa0.get();
    *(bf16x8*)&At[r1 * LAB + cg] = sa1.get();
    *(bf16x8*)&Bt[r0 * LAB + cg] = sb0.get();
    *(bf16x8*)&Bt[r1 * LAB + cg] = sb1.get();
    __syncthreads();
    if (k0 + 32 < K) {
      sa0.ld(A  + (long)(m0 + r0) * K + k0 + 32 + cg);
      sa1.ld(A  + (long)(m0 + r1) * K + k0 + 32 + cg);
      sb0.ld(Bm + (long)(n0 + r0) * K + k0 + 32 + cg);
      sb1.ld(Bm + (long)(n0 + r1) * K + k0 + 32 + cg);
    }

    bf16x8 af[4], bfv[4];
#pragma unroll
    for (int i = 0; i < 4; i++)
      af[i] = *(const bf16x8*)&At[(wm * 64 + i * 16 + l16) * LAB + quad * 8];
#pragma unroll
    for (int j = 0; j < 4; j++)
      bfv[j] = *(const bf16x8*)&Bt[(wn * 64 + j * 16 + l16) * LAB + quad * 8];
#pragma unroll
    for (int i = 0; i < 4; i++)
#pragma unroll
      for (int j = 0; j < 4; j++)
        acc[i][j] = __builtin_amdgcn_mfma_f32_16x16x32_bf16(af[i], bfv[j], acc[i][j], 0, 0, 0);
  }

#pragma unroll
  for (int i = 0; i < 4; i++) {
    const int rbase = m0 + wm * 64 + i * 16 + quad * 4;
#pragma unroll
    for (int j = 0; j < 4; j++) {
      const int col = n0 + wn * 64 + j * 16 + l16;
      float bv = 0.f;
      if (MODE == 0) bv = bias[col];
#pragma unroll
      for (int r = 0; r < 4; r++) {
        const int row = rbase + r;
        float v = acc[i][j][r];
        if (MODE == 0) {
          ((float*)Cv)[(long)row * ND + col] = v + bv;
        } else if (MODE == 1) {
          int b = row >> 11, s = row & 2047, h = col >> 6, d = col & 63;
          ((u16t*)Cv)[(((long)(b * NH + h)) * NS + s) * NDK + d] = f2bf(v);
        } else {
          int b = row >> 11, s = row & 2047, h = col >> 6, d = col & 63;
          ((u16t*)Cv)[(((long)(b * NH + h)) * NDK + d) * NS + s] = f2bf(v);
        }
      }
    }
  }
}

// ---------------------------------------------------------------------------
// Flash attention pass: per (b,h, 128-row q tile). 4 waves x 32 q rows.
// exp2-domain online softmax; DPP rotate-reduce; exact skip-rescale; swizzled
// [64][64] LDS tiles (conflict-free, verified R2); software-pipelined K/V
// staging. launch_bounds (256,3): (256,4) forced a 64-VGPR budget -> 600 MB
// of scratch spills per dispatch (R2). 3 waves/EU leaves ~170 VGPR headroom.
// ---------------------------------------------------------------------------
__global__ __launch_bounds__(256, 3)
void flash_ctx(const u16t* __restrict__ Qw, const u16t* __restrict__ Kw,
               const u16t* __restrict__ VTw, const int* __restrict__ mask,
               u16t* __restrict__ ctx, float* __restrict__ mo, float* __restrict__ lo)
{
  __shared__ __attribute__((aligned(16))) u16t Kt[64 * 64];
  __shared__ __attribute__((aligned(16))) u16t Vt[64 * 64];
  __shared__ __attribute__((aligned(16))) u16t Pt[4 * 32 * 64];
  __shared__ float biasl[NS];

  const int tid  = threadIdx.x;
  const int w    = tid >> 6;
  const int lane = tid & 63;
  const int quad = lane >> 4;
  const int l16  = lane & 15;
  const int bh   = blockIdx.y;        // b*16 + h
  const int b    = bh >> 4;
  const int h    = bh & 15;
  const int qw   = blockIdx.x * 128 + w * 32;
  const int pbase = w * 2048;

  for (int i = tid; i < NS; i += 256)
    biasl[i] = mask[b * NS + i] ? 0.f : NEGINF;

  // preload this wave's Q fragments (32 rows x 64 d) into registers
  bf16x8 qf[2][2];
#pragma unroll
  for (int g = 0; g < 2; g++)
#pragma unroll
    for (int kk = 0; kk < 2; kk++)
      qf[g][kk] = *(const bf16x8*)(Qw + ((long)bh * NS + qw + g * 16 + l16) * NDK + kk * 32 + quad * 8);

  const f32x4 fz = {0.f, 0.f, 0.f, 0.f};
  const f32x4 fm = {NEGINF, NEGINF, NEGINF, NEGINF};
  f32x4 cacc[2][4];
#pragma unroll
  for (int g = 0; g < 2; g++)
#pragma unroll
    for (int d = 0; d < 4; d++) cacc[g][d] = fz;
  f32x4 mrun[2] = {fm, fm};
  f32x4 lrun[2] = {fz, fz};

  // staging chunk map: chunk c (0..511) -> row c>>3 (0..63), colgrp (c&7)*8
  const int kr0 = tid >> 3, kc0 = (tid & 7) * 8;
  const int kr1 = kr0 + 32;
  const long kbase = (long)bh * NS;
  const long vbase = (long)bh * NDK;

  bf16x8 k0v = *(const bf16x8*)(Kw  + (kbase + kr0) * NDK + kc0);
  bf16x8 k1v = *(const bf16x8*)(Kw  + (kbase + kr1) * NDK + kc0);
  bf16x8 v0v = *(const bf16x8*)(VTw + (vbase + kr0) * NS + kc0);
  bf16x8 v1v = *(const bf16x8*)(VTw + (vbase + kr1) * NS + kc0);

  for (int kb = 0; kb < NS; kb += 64) {
    __syncthreads();
    *(bf16x8*)&Kt[swz(kr0, kc0)] = k0v;
    *(bf16x8*)&Kt[swz(kr1, kc0)] = k1v;
    *(bf16x8*)&Vt[swz(kr0, kc0)] = v0v;
    *(bf16x8*)&Vt[swz(kr1, kc0)] = v1v;
    __syncthreads();
    if (kb + 64 < NS) {   // prefetch next tile; latency hides under compute
      k0v = *(const bf16x8*)(Kw  + (kbase + kb + 64 + kr0) * NDK + kc0);
      k1v = *(const bf16x8*)(Kw  + (kbase + kb + 64 + kr1) * NDK + kc0);
      v0v = *(const bf16x8*)(VTw + (vbase + kr0) * NS + kb + 64 + kc0);
      v1v = *(const bf16x8*)(VTw + (vbase + kr1) * NS + kb + 64 + kc0);
    }

    // S = Q K^T (rows: q, cols: key)
    f32x4 s[2][4];
#pragma unroll
    for (int g = 0; g < 2; g++)
#pragma unroll
      for (int c = 0; c < 4; c++) {
        f32x4 a = fz;
#pragma unroll
        for (int kk = 0; kk < 2; kk++) {
          bf16x8 kf = *(const bf16x8*)&Kt[swz(c * 16 + l16, kk * 32 + quad * 8)];
          a = __builtin_amdgcn_mfma_f32_16x16x32_bf16(qf[g][kk], kf, a, 0, 0, 0);
        }
        s[g][c] = a;
      }

    float bias_c[4];
#pragma unroll
    for (int c = 0; c < 4; c++) bias_c[c] = biasl[kb + c * 16 + l16];

#pragma unroll
    for (int g = 0; g < 2; g++) {
#pragma unroll
      for (int c = 0; c < 4; c++)
#pragma unroll
        for (int r = 0; r < 4; r++)
          s[g][c][r] = s[g][c][r] * SCALE2 + bias_c[c];

      // row max: fold 4 col-frags, then DPP rotate-reduce over the 16 lanes
      f32x4 mx = s[g][0];
#pragma unroll
      for (int c = 1; c < 4; c++)
#pragma unroll
        for (int r = 0; r < 4; r++) mx[r] = fmaxf(mx[r], s[g][c][r]);
#pragma unroll
      for (int r = 0; r < 4; r++) {
        float x = mx[r];
        x = fmaxf(x, ROR16(x, 1));
        x = fmaxf(x, ROR16(x, 2));
        x = fmaxf(x, ROR16(x, 4));
        x = fmaxf(x, ROR16(x, 8));
        mx[r] = x;
      }

      // exact skip-rescale: only rescale if some row's max grew (alpha != 1)
      bool grow = (mx[0] > mrun[g][0]) | (mx[1] > mrun[g][1]) |
                  (mx[2] > mrun[g][2]) | (mx[3] > mrun[g][3]);
      if (__any((int)grow)) {
#pragma unroll
        for (int r = 0; r < 4; r++) {
          float mnew = fmaxf(mrun[g][r], mx[r]);
          float al = fexp2(mrun[g][r] - mnew);
          mrun[g][r] = mnew;
          lrun[g][r] *= al;
#pragma unroll
          for (int d = 0; d < 4; d++) cacc[g][d][r] *= al;
        }
      }

#pragma unroll
      for (int c = 0; c < 4; c++)
#pragma unroll
        for (int r = 0; r < 4; r++) s[g][c][r] = fexp2(s[g][c][r] - mrun[g][r]);

      f32x4 sm = fz;
#pragma unroll
      for (int c = 0; c < 4; c++)
#pragma unroll
        for (int r = 0; r < 4; r++) sm[r] += s[g][c][r];
#pragma unroll
      for (int r = 0; r < 4; r++) {
        float x = sm[r];
        x += ROR16(x, 1);
        x += ROR16(x, 2);
        x += ROR16(x, 4);
        x += ROR16(x, 8);
        lrun[g][r] += x;
      }

      // P -> LDS (A-operand layout: [q][key] row-major, swizzled)
#pragma unroll
      for (int c = 0; c < 4; c++)
#pragma unroll
        for (int r = 0; r < 4; r++)
          Pt[pbase + swz(g * 16 + quad * 4 + r, c * 16 + l16)] = f2bf(s[g][c][r]);
    }

    // context += P * V  (Pt region is per-wave; same-wave DS ops are in order)
#pragma unroll
    for (int g = 0; g < 2; g++)
#pragma unroll
      for (int d = 0; d < 4; d++)
#pragma unroll
        for (int kk = 0; kk < 2; kk++) {
          bf16x8 pf = *(const bf16x8*)&Pt[pbase + swz(g * 16 + l16, kk * 32 + quad * 8)];
          bf16x8 vf = *(const bf16x8*)&Vt[swz(d * 16 + l16, kk * 32 + quad * 8)];
          cacc[g][d] = __builtin_amdgcn_mfma_f32_16x16x32_bf16(pf, vf, cacc[g][d], 0, 0, 0);
        }
  }

  // epilogue: normalize, write context and (m,l)
#pragma unroll
  for (int g = 0; g < 2; g++) {
    f32x4 rinv;
#pragma unroll
    for (int r = 0; r < 4; r++) rinv[r] = 1.f / lrun[g][r];
#pragma unroll
    for (int d = 0; d < 4; d++)
#pragma unroll
      for (int r = 0; r < 4; r++) {
        int qg = qw + g * 16 + quad * 4 + r;
        int e  = h * NDK + d * 16 + l16;
        ctx[((long)(b * NS + qg)) * ND + e] = f2bf(cacc[g][d][r] * rinv[r]);
      }
    if (l16 == 0) {
#pragma unroll
      for (int r = 0; r < 4; r++) {
        int qg = qw + g * 16 + quad * 4 + r;
        mo[(long)bh * NS + qg] = mrun[g][r];
        lo[(long)bh * NS + qg] = lrun[g][r];
      }
    }
  }
}

// ---------------------------------------------------------------------------
// probs_mean: per (b, 128x128 score tile), loop all 16 heads recomputing
// S = Q K^T, p = exp2(s*SCALE2 + maskbias - m)/l, accumulate mean, fp32 out.
// Swizzled [128][64] tiles (no pad) -> LDS 48.5 KB -> 3 blocks/CU.
// ---------------------------------------------------------------------------
__global__ __launch_bounds__(256, 3)
void probs_mean(const u16t* __restrict__ Qw, const u16t* __restrict__ Kw,
                const int* __restrict__ mask, const float* __restrict__ mo,
                const float* __restrict__ lo, float* __restrict__ outp)
{
  __shared__ __attribute__((aligned(16))) u16t Qt[128 * 64];
  __shared__ __attribute__((aligned(16))) u16t Kt2[128 * 64];
  __shared__ float ml[NH * 128];
  __shared__ float li[NH * 128];
  __shared__ float biasl[128];

  const int tid  = threadIdx.x;
  const int w    = tid >> 6;
  const int lane = tid & 63;
  const int quad = lane >> 4;
  const int l16  = lane & 15;
  const int wm   = w >> 1, wn = w & 1;
  const int b  = blockIdx.z;
  const int q0 = blockIdx.y * 128;
  const int k0 = blockIdx.x * 128;

  for (int i = tid; i < NH * 128; i += 256) {
    int hh = i >> 7, r = i & 127;
    ml[i] = mo[((long)(b * NH + hh)) * NS + q0 + r];
    li[i] = 1.f / lo[((long)(b * NH + hh)) * NS + q0 + r];
  }
  for (int i = tid; i < 128; i += 256)
    biasl[i] = mask[b * NS + k0 + i] ? 0.f : NEGINF;

  const f32x4 fz = {0.f, 0.f, 0.f, 0.f};
  f32x4 acc[4][4];
#pragma unroll
  for (int i = 0; i < 4; i++)
#pragma unroll
    for (int j = 0; j < 4; j++) acc[i][j] = fz;

  bf16x8 qv[4], kv[4];
#pragma unroll
  for (int rr = 0; rr < 4; rr++) {
    int idx = rr * 256 + tid;
    int row = idx >> 3, off = (idx & 7) * 8;
    qv[rr] = *(const bf16x8*)(Qw + ((long)(b * NH) * NS + q0 + row) * NDK + off);
    kv[rr] = *(const bf16x8*)(Kw + ((long)(b * NH) * NS + k0 + row) * NDK + off);
  }

  for (int hh = 0; hh < NH; hh++) {
    __syncthreads();
#pragma unroll
    for (int rr = 0; rr < 4; rr++) {
      int idx = rr * 256 + tid;
      int row = idx >> 3, off = (idx & 7) * 8;
      *(bf16x8*)&Qt[swz(row, off)]  = qv[rr];
      *(bf16x8*)&Kt2[swz(row, off)] = kv[rr];
    }
    __syncthreads();
    if (hh + 1 < NH) {
#pragma unroll
      for (int rr = 0; rr < 4; rr++) {
        int idx = rr * 256 + tid;
        int row = idx >> 3, off = (idx & 7) * 8;
        qv[rr] = *(const bf16x8*)(Qw + ((long)(b * NH + hh + 1) * NS + q0 + row) * NDK + off);
        kv[rr] = *(const bf16x8*)(Kw + ((long)(b * NH + hh + 1) * NS + k0 + row) * NDK + off);
      }
    }

    bf16x8 af[4][2], bfv[4][2];
#pragma unroll
    for (int i = 0; i < 4; i++)
#pragma unroll
      for (int kk = 0; kk < 2; kk++) {
        af[i][kk]  = *(const bf16x8*)&Qt[swz(wm * 64 + i * 16 + l16, kk * 32 + quad * 8)];
        bfv[i][kk] = *(const bf16x8*)&Kt2[swz(wn * 64 + i * 16 + l16, kk * 32 + quad * 8)];
      }
#pragma unroll
    for (int i = 0; i < 4; i++)
#pragma unroll
      for (int j = 0; j < 4; j++) {
        f32x4 s = fz;
#pragma unroll
        for (int kk = 0; kk < 2; kk++)
          s = __builtin_amdgcn_mfma_f32_16x16x32_bf16(af[i][kk], bfv[j][kk], s, 0, 0, 0);
        const float bias_c = biasl[wn * 64 + j * 16 + l16];
#pragma unroll
        for (int r = 0; r < 4; r++) {
          int rowb = wm * 64 + i * 16 + quad * 4 + r;
          float p = fexp2(s[r] * SCALE2 + bias_c - ml[hh * 128 + rowb]) * li[hh * 128 + rowb];
          acc[i][j][r] += p;
        }
      }
  }

#pragma unroll
  for (int i = 0; i < 4; i++)
#pragma unroll
    for (int j = 0; j < 4; j++)
#pragma unroll
      for (int r = 0; r < 4; r++) {
        int row = q0 + wm * 64 + i * 16 + quad * 4 + r;
        int col = k0 + wn * 64 + j * 16 + l16;
        outp[((long)(b * NS + row)) * NS + col] = acc[i][j][r] * (1.f / 16.f);
      }
}

// ---------------------------------------------------------------------------
extern "C" void kernel_launch(void* const* d_in, const int* in_sizes, int n_in,
                              void* d_out, int out_size, void* d_ws, size_t ws_size,
                              hipStream_t stream)
{
  (void)in_sizes; (void)n_in; (void)out_size; (void)ws_size;
  const float* query = (const float*)d_in[0];
  const float* keyt  = (const float*)d_in[1];
  const float* value = (const float*)d_in[2];
  const int*   mask  = (const int*)d_in[3];
  const float* Wq = (const float*)d_in[4];
  const float* Wk = (const float*)d_in[5];
  const float* Wv = (const float*)d_in[6];
  const float* Wo = (const float*)d_in[7];
  const float* bo = (const float*)d_in[8];

  float* out  = (float*)d_out;                     // [B,S,D] fp32
  float* outp = out + (long)NB * NS * ND;          // [B,S,S] fp32

  u16t* q_ws  = (u16t*)d_ws;                       // [B,H,S,dk] bf16
  u16t* k_ws  = q_ws + (long)NB * NH * NS * NDK;   // [B,H,S,dk] bf16
  u16t* vt_ws = k_ws + (long)NB * NH * NS * NDK;   // [B,H,dk,S] bf16
  float* m_ws = (float*)(vt_ws + (long)NB * NH * NS * NDK);
  float* l_ws = m_ws + (long)NB * NH * NS;
  // ctx scratch (bf16) lives in the outp region of d_out; it is fully
  // consumed by the output GEMM before probs_mean overwrites the region.
  u16t* ctx_ws = (u16t*)outp;

  dim3 blk(256);
  gemm_nt<float, 1><<<dim3(64, 8), blk, 0, stream>>>(query, Wq, q_ws, nullptr);
  gemm_nt<float, 1><<<dim3(64, 8), blk, 0, stream>>>(keyt,  Wk, k_ws, nullptr);
  gemm_nt<float, 2><<<dim3(64, 8), blk, 0, stream>>>(value, Wv, vt_ws, nullptr);
  flash_ctx<<<dim3(NS / 128, NB * NH), blk, 0, stream>>>(q_ws, k_ws, vt_ws, mask,
                                                         ctx_ws, m_ws, l_ws);
  gemm_nt<u16t, 0><<<dim3(64, 8), blk, 0, stream>>>(ctx_ws, Wo, out, bo);
  probs_mean<<<dim3(NS / 128, NS / 128, NB), blk, 0, stream>>>(q_ws, k_ws, mask,
                                                               m_ws, l_ws, outp);
}

// Round 4
// 599.360 us; speedup vs baseline: 1.4292x; 1.1062x over previous
//
#include <hip/hip_runtime.h>

typedef unsigned short u16t;
typedef __bf16 bf16x8 __attribute__((ext_vector_type(8)));
typedef float f32x4 __attribute__((ext_vector_type(4)));

#define NB 4
#define NS 2048
#define ND 1024
#define NH 16
#define NDK 64
#define NEGINF -1.0e9f
// softmax runs in exp2 domain: SCALE2 = 0.125 * log2(e)
#define SCALE2 0.18033688011112042f

// padded LDS row stride for gemm (32-wide tiles): 40 elem = 80B, 5 granules,
// coprime with 8 -> conflict-free frag reads.
#define LAB 40

__device__ __forceinline__ float fexp2(float x) { return __builtin_amdgcn_exp2f(x); }

// native bf16 convert (RNE via v_cvt_pk_bf16_f32; 1 inst vs 3 bit-ops)
__device__ __forceinline__ u16t f2bf(float f) {
  return __builtin_bit_cast(u16t, (__bf16)f);
}

// XOR-swizzle index for [*][64] u16 tiles: rotates 16B granules within each
// 8-row stripe -> conflict-free b128 reads at 128B row stride (no padding).
// Verified: R2/R3 flash SQ_LDS_BANK_CONFLICT == 0 with this on both sides.
__device__ __forceinline__ int swz(int row, int col) {
  return row * 64 + (col ^ ((row & 7) << 3));
}

// register staging helpers (raw loads now, convert at LDS-store time)
template<typename TA> struct Stg;
template<> struct Stg<float> {
  f32x4 lo, hi;
  __device__ __forceinline__ void ld(const float* p) {
    lo = *(const f32x4*)p; hi = *(const f32x4*)(p + 4);
  }
  __device__ __forceinline__ bf16x8 get() const {
    bf16x8 r;
    r[0] = (__bf16)lo[0]; r[1] = (__bf16)lo[1]; r[2] = (__bf16)lo[2]; r[3] = (__bf16)lo[3];
    r[4] = (__bf16)hi[0]; r[5] = (__bf16)hi[1]; r[6] = (__bf16)hi[2]; r[7] = (__bf16)hi[3];
    return r;
  }
};
template<> struct Stg<u16t> {
  bf16x8 v;
  __device__ __forceinline__ void ld(const u16t* p) { v = *(const bf16x8*)p; }
  __device__ __forceinline__ bf16x8 get() const { return v; }
};

// ---------------------------------------------------------------------------
// NT GEMM: C[M,N] = A[M,K] * B[N,K]^T ; M=8192, N=K=1024, bf16 MFMA, fp32 acc.
// MODE 0: C fp32 row-major [M,N] + bias[col]   (output projection -> d_out)
// MODE 1: C bf16 scatter to [B,H,S,dk]         (Q/K projections -> ws)
// MODE 2: C bf16 scatter to [B,H,dk,S]         (V projection, transposed -> ws)
// Software-pipelined: next K-step's global loads issue before the MFMA block.
// ---------------------------------------------------------------------------
template<typename TA, int MODE>
__global__ __launch_bounds__(256, 2)
void gemm_nt(const TA* __restrict__ A, const float* __restrict__ Bm,
             void* __restrict__ Cv, const float* __restrict__ bias)
{
  const int K = 1024;
  __shared__ __attribute__((aligned(16))) u16t At[128 * LAB];
  __shared__ __attribute__((aligned(16))) u16t Bt[128 * LAB];

  const int tid  = threadIdx.x;
  const int w    = tid >> 6;
  const int lane = tid & 63;
  const int quad = lane >> 4;
  const int l16  = lane & 15;
  const int wm   = w >> 1, wn = w & 1;
  const int m0   = blockIdx.x * 128;
  const int n0   = blockIdx.y * 128;

  const f32x4 fz = {0.f, 0.f, 0.f, 0.f};
  f32x4 acc[4][4];
#pragma unroll
  for (int i = 0; i < 4; i++)
#pragma unroll
    for (int j = 0; j < 4; j++) acc[i][j] = fz;

  // staging chunk map: chunk c (0..511) -> row c>>2 (0..127), colgrp (c&3)*8
  const int r0 = tid >> 2, cg = (tid & 3) * 8;
  const int r1 = r0 + 64;

  Stg<TA> sa0, sa1; Stg<float> sb0, sb1;
  sa0.ld(A  + (long)(m0 + r0) * K + cg);
  sa1.ld(A  + (long)(m0 + r1) * K + cg);
  sb0.ld(Bm + (long)(n0 + r0) * K + cg);
  sb1.ld(Bm + (long)(n0 + r1) * K + cg);

  for (int k0 = 0; k0 < K; k0 += 32) {
    __syncthreads();
    *(bf16x8*)&At[r0 * LAB + cg] = sa0.get();
    *(bf16x8*)&At[r1 * LAB + cg] = sa1.get();
    *(bf16x8*)&Bt[r0 * LAB + cg] = sb0.get();
    *(bf16x8*)&Bt[r1 * LAB + cg] = sb1.get();
    __syncthreads();
    if (k0 + 32 < K) {
      sa0.ld(A  + (long)(m0 + r0) * K + k0 + 32 + cg);
      sa1.ld(A  + (long)(m0 + r1) * K + k0 + 32 + cg);
      sb0.ld(Bm + (long)(n0 + r0) * K + k0 + 32 + cg);
      sb1.ld(Bm + (long)(n0 + r1) * K + k0 + 32 + cg);
    }

    bf16x8 af[4], bfv[4];
#pragma unroll
    for (int i = 0; i < 4; i++)
      af[i] = *(const bf16x8*)&At[(wm * 64 + i * 16 + l16) * LAB + quad * 8];
#pragma unroll
    for (int j = 0; j < 4; j++)
      bfv[j] = *(const bf16x8*)&Bt[(wn * 64 + j * 16 + l16) * LAB + quad * 8];
#pragma unroll
    for (int i = 0; i < 4; i++)
#pragma unroll
      for (int j = 0; j < 4; j++)
        acc[i][j] = __builtin_amdgcn_mfma_f32_16x16x32_bf16(af[i], bfv[j], acc[i][j], 0, 0, 0);
  }

#pragma unroll
  for (int i = 0; i < 4; i++) {
    const int rbase = m0 + wm * 64 + i * 16 + quad * 4;
#pragma unroll
    for (int j = 0; j < 4; j++) {
      const int col = n0 + wn * 64 + j * 16 + l16;
      float bv = 0.f;
      if (MODE == 0) bv = bias[col];
#pragma unroll
      for (int r = 0; r < 4; r++) {
        const int row = rbase + r;
        float v = acc[i][j][r];
        if (MODE == 0) {
          ((float*)Cv)[(long)row * ND + col] = v + bv;
        } else if (MODE == 1) {
          int b = row >> 11, s = row & 2047, h = col >> 6, d = col & 63;
          ((u16t*)Cv)[(((long)(b * NH + h)) * NS + s) * NDK + d] = f2bf(v);
        } else {
          int b = row >> 11, s = row & 2047, h = col >> 6, d = col & 63;
          ((u16t*)Cv)[(((long)(b * NH + h)) * NDK + d) * NS + s] = f2bf(v);
        }
      }
    }
  }
}

// ---------------------------------------------------------------------------
// Flash attention pass: per (b,h, 128-row q tile). 4 waves x 32 q rows.
// exp2-domain online softmax (unconditional rescale: straight-line, low reg
// pressure); shfl_xor reduces (LDS pipe, which is idle); swizzled [64][64]
// LDS tiles (conflict-free, verified); software-pipelined K/V staging.
// Per-g P->LDS->PV round-trip: halves live softmax state and Pt (LDS 32 KB).
// R3 lesson: skip-rescale branch + DPP pushed live ranges past the (256,3)
// unified VGPR budget -> per-iter scratch spills (+23 MB WRITE_SIZE).
// ---------------------------------------------------------------------------
__global__ __launch_bounds__(256, 3)
void flash_ctx(const u16t* __restrict__ Qw, const u16t* __restrict__ Kw,
               const u16t* __restrict__ VTw, const int* __restrict__ mask,
               u16t* __restrict__ ctx, float* __restrict__ mo, float* __restrict__ lo)
{
  __shared__ __attribute__((aligned(16))) u16t Kt[64 * 64];
  __shared__ __attribute__((aligned(16))) u16t Vt[64 * 64];
  __shared__ __attribute__((aligned(16))) u16t Pt[4 * 16 * 64];
  __shared__ float biasl[NS];

  const int tid  = threadIdx.x;
  const int w    = tid >> 6;
  const int lane = tid & 63;
  const int quad = lane >> 4;
  const int l16  = lane & 15;
  const int bh   = blockIdx.y;        // b*16 + h
  const int b    = bh >> 4;
  const int h    = bh & 15;
  const int qw   = blockIdx.x * 128 + w * 32;
  const int pbase = w * 1024;         // per-wave 16x64 P tile

  for (int i = tid; i < NS; i += 256)
    biasl[i] = mask[b * NS + i] ? 0.f : NEGINF;

  // preload this wave's Q fragments (32 rows x 64 d) into registers
  bf16x8 qf[2][2];
#pragma unroll
  for (int g = 0; g < 2; g++)
#pragma unroll
    for (int kk = 0; kk < 2; kk++)
      qf[g][kk] = *(const bf16x8*)(Qw + ((long)bh * NS + qw + g * 16 + l16) * NDK + kk * 32 + quad * 8);

  const f32x4 fz = {0.f, 0.f, 0.f, 0.f};
  const f32x4 fm = {NEGINF, NEGINF, NEGINF, NEGINF};
  f32x4 cacc[2][4];
#pragma unroll
  for (int g = 0; g < 2; g++)
#pragma unroll
    for (int d = 0; d < 4; d++) cacc[g][d] = fz;
  f32x4 mrun[2] = {fm, fm};
  f32x4 lrun[2] = {fz, fz};

  // staging chunk map: chunk c (0..511) -> row c>>3 (0..63), colgrp (c&7)*8
  const int kr0 = tid >> 3, kc0 = (tid & 7) * 8;
  const int kr1 = kr0 + 32;
  const long kbase = (long)bh * NS;
  const long vbase = (long)bh * NDK;

  bf16x8 k0v = *(const bf16x8*)(Kw  + (kbase + kr0) * NDK + kc0);
  bf16x8 k1v = *(const bf16x8*)(Kw  + (kbase + kr1) * NDK + kc0);
  bf16x8 v0v = *(const bf16x8*)(VTw + (vbase + kr0) * NS + kc0);
  bf16x8 v1v = *(const bf16x8*)(VTw + (vbase + kr1) * NS + kc0);

  for (int kb = 0; kb < NS; kb += 64) {
    __syncthreads();
    *(bf16x8*)&Kt[swz(kr0, kc0)] = k0v;
    *(bf16x8*)&Kt[swz(kr1, kc0)] = k1v;
    *(bf16x8*)&Vt[swz(kr0, kc0)] = v0v;
    *(bf16x8*)&Vt[swz(kr1, kc0)] = v1v;
    __syncthreads();
    if (kb + 64 < NS) {   // prefetch next tile; latency hides under compute
      k0v = *(const bf16x8*)(Kw  + (kbase + kb + 64 + kr0) * NDK + kc0);
      k1v = *(const bf16x8*)(Kw  + (kbase + kb + 64 + kr1) * NDK + kc0);
      v0v = *(const bf16x8*)(VTw + (vbase + kr0) * NS + kb + 64 + kc0);
      v1v = *(const bf16x8*)(VTw + (vbase + kr1) * NS + kb + 64 + kc0);
    }

    float bias_c[4];
#pragma unroll
    for (int c = 0; c < 4; c++) bias_c[c] = biasl[kb + c * 16 + l16];

#pragma unroll
    for (int g = 0; g < 2; g++) {
      // S = Q K^T (rows: q, cols: key) for this 16-row group
      f32x4 s[4];
#pragma unroll
      for (int c = 0; c < 4; c++) {
        f32x4 a = fz;
#pragma unroll
        for (int kk = 0; kk < 2; kk++) {
          bf16x8 kf = *(const bf16x8*)&Kt[swz(c * 16 + l16, kk * 32 + quad * 8)];
          a = __builtin_amdgcn_mfma_f32_16x16x32_bf16(qf[g][kk], kf, a, 0, 0, 0);
        }
        s[c] = a;
      }

#pragma unroll
      for (int c = 0; c < 4; c++)
#pragma unroll
        for (int r = 0; r < 4; r++)
          s[c][r] = s[c][r] * SCALE2 + bias_c[c];

      // row max across 4 col-frags then across the 16 col lanes
      f32x4 mx = s[0];
#pragma unroll
      for (int c = 1; c < 4; c++)
#pragma unroll
        for (int r = 0; r < 4; r++) mx[r] = fmaxf(mx[r], s[c][r]);
#pragma unroll
      for (int off = 1; off < 16; off <<= 1)
#pragma unroll
        for (int r = 0; r < 4; r++) mx[r] = fmaxf(mx[r], __shfl_xor(mx[r], off, 64));

      f32x4 alpha;
#pragma unroll
      for (int r = 0; r < 4; r++) {
        float mnew = fmaxf(mrun[g][r], mx[r]);
        alpha[r] = fexp2(mrun[g][r] - mnew);
        mrun[g][r] = mnew;
      }
#pragma unroll
      for (int c = 0; c < 4; c++)
#pragma unroll
        for (int r = 0; r < 4; r++) s[c][r] = fexp2(s[c][r] - mrun[g][r]);

      f32x4 sm = fz;
#pragma unroll
      for (int c = 0; c < 4; c++)
#pragma unroll
        for (int r = 0; r < 4; r++) sm[r] += s[c][r];
#pragma unroll
      for (int off = 1; off < 16; off <<= 1)
#pragma unroll
        for (int r = 0; r < 4; r++) sm[r] += __shfl_xor(sm[r], off, 64);
#pragma unroll
      for (int r = 0; r < 4; r++) lrun[g][r] = lrun[g][r] * alpha[r] + sm[r];
#pragma unroll
      for (int d = 0; d < 4; d++)
#pragma unroll
        for (int r = 0; r < 4; r++) cacc[g][d][r] *= alpha[r];

      // P(g) -> LDS (A-operand layout: [q][key] row-major, swizzled)
#pragma unroll
      for (int c = 0; c < 4; c++)
#pragma unroll
        for (int r = 0; r < 4; r++)
          Pt[pbase + swz(quad * 4 + r, c * 16 + l16)] = f2bf(s[c][r]);

      // context(g) += P(g) * V  (per-wave Pt; same-wave DS ops are in order)
#pragma unroll
      for (int d = 0; d < 4; d++)
#pragma unroll
        for (int kk = 0; kk < 2; kk++) {
          bf16x8 pf = *(const bf16x8*)&Pt[pbase + swz(l16, kk * 32 + quad * 8)];
          bf16x8 vf = *(const bf16x8*)&Vt[swz(d * 16 + l16, kk * 32 + quad * 8)];
          cacc[g][d] = __builtin_amdgcn_mfma_f32_16x16x32_bf16(pf, vf, cacc[g][d], 0, 0, 0);
        }
    }
  }

  // epilogue: normalize, write context and (m,l)
#pragma unroll
  for (int g = 0; g < 2; g++) {
    f32x4 rinv;
#pragma unroll
    for (int r = 0; r < 4; r++) rinv[r] = 1.f / lrun[g][r];
#pragma unroll
    for (int d = 0; d < 4; d++)
#pragma unroll
      for (int r = 0; r < 4; r++) {
        int qg = qw + g * 16 + quad * 4 + r;
        int e  = h * NDK + d * 16 + l16;
        ctx[((long)(b * NS + qg)) * ND + e] = f2bf(cacc[g][d][r] * rinv[r]);
      }
    if (l16 == 0) {
#pragma unroll
      for (int r = 0; r < 4; r++) {
        int qg = qw + g * 16 + quad * 4 + r;
        mo[(long)bh * NS + qg] = mrun[g][r];
        lo[(long)bh * NS + qg] = lrun[g][r];
      }
    }
  }
}

// ---------------------------------------------------------------------------
// probs_mean: per (b, 128x128 score tile), loop all 16 heads recomputing
// S = Q K^T, p = exp2(s*SCALE2 + maskbias - m)/l, accumulate mean, fp32 out.
// Swizzled [128][64] tiles (no pad); software-pipelined head staging.
// ---------------------------------------------------------------------------
__global__ __launch_bounds__(256, 3)
void probs_mean(const u16t* __restrict__ Qw, const u16t* __restrict__ Kw,
                const int* __restrict__ mask, const float* __restrict__ mo,
                const float* __restrict__ lo, float* __restrict__ outp)
{
  __shared__ __attribute__((aligned(16))) u16t Qt[128 * 64];
  __shared__ __attribute__((aligned(16))) u16t Kt2[128 * 64];
  __shared__ float ml[NH * 128];
  __shared__ float li[NH * 128];
  __shared__ float biasl[128];

  const int tid  = threadIdx.x;
  const int w    = tid >> 6;
  const int lane = tid & 63;
  const int quad = lane >> 4;
  const int l16  = lane & 15;
  const int wm   = w >> 1, wn = w & 1;
  const int b  = blockIdx.z;
  const int q0 = blockIdx.y * 128;
  const int k0 = blockIdx.x * 128;

  for (int i = tid; i < NH * 128; i += 256) {
    int hh = i >> 7, r = i & 127;
    ml[i] = mo[((long)(b * NH + hh)) * NS + q0 + r];
    li[i] = 1.f / lo[((long)(b * NH + hh)) * NS + q0 + r];
  }
  for (int i = tid; i < 128; i += 256)
    biasl[i] = mask[b * NS + k0 + i] ? 0.f : NEGINF;

  const f32x4 fz = {0.f, 0.f, 0.f, 0.f};
  f32x4 acc[4][4];
#pragma unroll
  for (int i = 0; i < 4; i++)
#pragma unroll
    for (int j = 0; j < 4; j++) acc[i][j] = fz;

  bf16x8 qv[4], kv[4];
#pragma unroll
  for (int rr = 0; rr < 4; rr++) {
    int idx = rr * 256 + tid;
    int row = idx >> 3, off = (idx & 7) * 8;
    qv[rr] = *(const bf16x8*)(Qw + ((long)(b * NH) * NS + q0 + row) * NDK + off);
    kv[rr] = *(const bf16x8*)(Kw + ((long)(b * NH) * NS + k0 + row) * NDK + off);
  }

  for (int hh = 0; hh < NH; hh++) {
    __syncthreads();
#pragma unroll
    for (int rr = 0; rr < 4; rr++) {
      int idx = rr * 256 + tid;
      int row = idx >> 3, off = (idx & 7) * 8;
      *(bf16x8*)&Qt[swz(row, off)]  = qv[rr];
      *(bf16x8*)&Kt2[swz(row, off)] = kv[rr];
    }
    __syncthreads();
    if (hh + 1 < NH) {
#pragma unroll
      for (int rr = 0; rr < 4; rr++) {
        int idx = rr * 256 + tid;
        int row = idx >> 3, off = (idx & 7) * 8;
        qv[rr] = *(const bf16x8*)(Qw + ((long)(b * NH + hh + 1) * NS + q0 + row) * NDK + off);
        kv[rr] = *(const bf16x8*)(Kw + ((long)(b * NH + hh + 1) * NS + k0 + row) * NDK + off);
      }
    }

    bf16x8 af[4][2], bfv[4][2];
#pragma unroll
    for (int i = 0; i < 4; i++)
#pragma unroll
      for (int kk = 0; kk < 2; kk++) {
        af[i][kk]  = *(const bf16x8*)&Qt[swz(wm * 64 + i * 16 + l16, kk * 32 + quad * 8)];
        bfv[i][kk] = *(const bf16x8*)&Kt2[swz(wn * 64 + i * 16 + l16, kk * 32 + quad * 8)];
      }
#pragma unroll
    for (int i = 0; i < 4; i++)
#pragma unroll
      for (int j = 0; j < 4; j++) {
        f32x4 s = fz;
#pragma unroll
        for (int kk = 0; kk < 2; kk++)
          s = __builtin_amdgcn_mfma_f32_16x16x32_bf16(af[i][kk], bfv[j][kk], s, 0, 0, 0);
        const float bias_c = biasl[wn * 64 + j * 16 + l16];
#pragma unroll
        for (int r = 0; r < 4; r++) {
          int rowb = wm * 64 + i * 16 + quad * 4 + r;
          float p = fexp2(s[r] * SCALE2 + bias_c - ml[hh * 128 + rowb]) * li[hh * 128 + rowb];
          acc[i][j][r] += p;
        }
      }
  }

#pragma unroll
  for (int i = 0; i < 4; i++)
#pragma unroll
    for (int j = 0; j < 4; j++)
#pragma unroll
      for (int r = 0; r < 4; r++) {
        int row = q0 + wm * 64 + i * 16 + quad * 4 + r;
        int col = k0 + wn * 64 + j * 16 + l16;
        outp[((long)(b * NS + row)) * NS + col] = acc[i][j][r] * (1.f / 16.f);
      }
}

// ---------------------------------------------------------------------------
extern "C" void kernel_launch(void* const* d_in, const int* in_sizes, int n_in,
                              void* d_out, int out_size, void* d_ws, size_t ws_size,
                              hipStream_t stream)
{
  (void)in_sizes; (void)n_in; (void)out_size; (void)ws_size;
  const float* query = (const float*)d_in[0];
  const float* keyt  = (const float*)d_in[1];
  const float* value = (const float*)d_in[2];
  const int*   mask  = (const int*)d_in[3];
  const float* Wq = (const float*)d_in[4];
  const float* Wk = (const float*)d_in[5];
  const float* Wv = (const float*)d_in[6];
  const float* Wo = (const float*)d_in[7];
  const float* bo = (const float*)d_in[8];

  float* out  = (float*)d_out;                     // [B,S,D] fp32
  float* outp = out + (long)NB * NS * ND;          // [B,S,S] fp32

  u16t* q_ws  = (u16t*)d_ws;                       // [B,H,S,dk] bf16
  u16t* k_ws  = q_ws + (long)NB * NH * NS * NDK;   // [B,H,S,dk] bf16
  u16t* vt_ws = k_ws + (long)NB * NH * NS * NDK;   // [B,H,dk,S] bf16
  float* m_ws = (float*)(vt_ws + (long)NB * NH * NS * NDK);
  float* l_ws = m_ws + (long)NB * NH * NS;
  // ctx scratch (bf16) lives in the outp region of d_out; it is fully
  // consumed by the output GEMM before probs_mean overwrites the region.
  u16t* ctx_ws = (u16t*)outp;

  dim3 blk(256);
  gemm_nt<float, 1><<<dim3(64, 8), blk, 0, stream>>>(query, Wq, q_ws, nullptr);
  gemm_nt<float, 1><<<dim3(64, 8), blk, 0, stream>>>(keyt,  Wk, k_ws, nullptr);
  gemm_nt<float, 2><<<dim3(64, 8), blk, 0, stream>>>(value, Wv, vt_ws, nullptr);
  flash_ctx<<<dim3(NS / 128, NB * NH), blk, 0, stream>>>(q_ws, k_ws, vt_ws, mask,
                                                         ctx_ws, m_ws, l_ws);
  gemm_nt<u16t, 0><<<dim3(64, 8), blk, 0, stream>>>(ctx_ws, Wo, out, bo);
  probs_mean<<<dim3(NS / 128, NS / 128, NB), blk, 0, stream>>>(q_ws, k_ws, mask,
                                                               m_ws, l_ws, outp);
}

// Round 5
// 579.015 us; speedup vs baseline: 1.4794x; 1.0351x over previous
//
#include <hip/hip_runtime.h>

typedef unsigned short u16t;
typedef __bf16 bf16x8 __attribute__((ext_vector_type(8)));
typedef float f32x4 __attribute__((ext_vector_type(4)));

#define NB 4
#define NS 2048
#define ND 1024
#define NH 16
#define NDK 64
#define NEGINF -1.0e9f
// softmax runs in exp2 domain: SCALE2 = 0.125 * log2(e)
#define SCALE2 0.18033688011112042f

// padded LDS row stride for gemm (32-wide tiles): 40 elem = 80B, 5 granules,
// coprime with 8 -> conflict-free frag reads.
#define LAB 40

__device__ __forceinline__ float fexp2(float x) { return __builtin_amdgcn_exp2f(x); }

// native bf16 convert (RNE via v_cvt_pk_bf16_f32; 1 inst vs 3 bit-ops)
__device__ __forceinline__ u16t f2bf(float f) {
  return __builtin_bit_cast(u16t, (__bf16)f);
}

// DPP rotate within 16-lane rows (softmax reduce: VALU pipe, ~3 cyc/step vs
// ~35 cyc ds_bpermute for shfl). Correctness verified in R2 (absmax identical).
#define ROR16(x, n) __builtin_bit_cast(float, __builtin_amdgcn_update_dpp(     \
    __builtin_bit_cast(int, (x)), __builtin_bit_cast(int, (x)),                \
    0x120 + (n), 0xF, 0xF, false))

// XOR-swizzle index for [*][64] u16 tiles: rotates 16B granules within each
// 8-row stripe -> conflict-free b128 reads at 128B row stride (no padding).
// Verified: R2/R3/R4 flash SQ_LDS_BANK_CONFLICT == 0 with this on both sides.
__device__ __forceinline__ int swz(int row, int col) {
  return row * 64 + (col ^ ((row & 7) << 3));
}

// register staging helpers (raw loads now, convert at LDS-store time)
template<typename TA> struct Stg;
template<> struct Stg<float> {
  f32x4 lo, hi;
  __device__ __forceinline__ void ld(const float* p) {
    lo = *(const f32x4*)p; hi = *(const f32x4*)(p + 4);
  }
  __device__ __forceinline__ bf16x8 get() const {
    bf16x8 r;
    r[0] = (__bf16)lo[0]; r[1] = (__bf16)lo[1]; r[2] = (__bf16)lo[2]; r[3] = (__bf16)lo[3];
    r[4] = (__bf16)hi[0]; r[5] = (__bf16)hi[1]; r[6] = (__bf16)hi[2]; r[7] = (__bf16)hi[3];
    return r;
  }
};
template<> struct Stg<u16t> {
  bf16x8 v;
  __device__ __forceinline__ void ld(const u16t* p) { v = *(const bf16x8*)p; }
  __device__ __forceinline__ bf16x8 get() const { return v; }
};

// ---------------------------------------------------------------------------
// NT GEMM: C[M,N] = A[M,K] * B[N,K]^T ; M=8192, N=K=1024, bf16 MFMA, fp32 acc.
// MODE 0: C fp32 row-major [M,N] + bias[col]   (output projection -> d_out)
// MODE 1: C bf16 scatter to [B,H,S,dk]         (Q/K projections -> ws)
// MODE 2: C bf16 scatter to [B,H,dk,S]         (V projection, transposed -> ws)
// Software-pipelined: next K-step's global loads issue before the MFMA block.
// ---------------------------------------------------------------------------
template<typename TA, int MODE>
__global__ __launch_bounds__(256, 2)
void gemm_nt(const TA* __restrict__ A, const float* __restrict__ Bm,
             void* __restrict__ Cv, const float* __restrict__ bias)
{
  const int K = 1024;
  __shared__ __attribute__((aligned(16))) u16t At[128 * LAB];
  __shared__ __attribute__((aligned(16))) u16t Bt[128 * LAB];

  const int tid  = threadIdx.x;
  const int w    = tid >> 6;
  const int lane = tid & 63;
  const int quad = lane >> 4;
  const int l16  = lane & 15;
  const int wm   = w >> 1, wn = w & 1;
  const int m0   = blockIdx.x * 128;
  const int n0   = blockIdx.y * 128;

  const f32x4 fz = {0.f, 0.f, 0.f, 0.f};
  f32x4 acc[4][4];
#pragma unroll
  for (int i = 0; i < 4; i++)
#pragma unroll
    for (int j = 0; j < 4; j++) acc[i][j] = fz;

  // staging chunk map: chunk c (0..511) -> row c>>2 (0..127), colgrp (c&3)*8
  const int r0 = tid >> 2, cg = (tid & 3) * 8;
  const int r1 = r0 + 64;

  Stg<TA> sa0, sa1; Stg<float> sb0, sb1;
  sa0.ld(A  + (long)(m0 + r0) * K + cg);
  sa1.ld(A  + (long)(m0 + r1) * K + cg);
  sb0.ld(Bm + (long)(n0 + r0) * K + cg);
  sb1.ld(Bm + (long)(n0 + r1) * K + cg);

  for (int k0 = 0; k0 < K; k0 += 32) {
    __syncthreads();
    *(bf16x8*)&At[r0 * LAB + cg] = sa0.get();
    *(bf16x8*)&At[r1 * LAB + cg] = sa1.get();
    *(bf16x8*)&Bt[r0 * LAB + cg] = sb0.get();
    *(bf16x8*)&Bt[r1 * LAB + cg] = sb1.get();
    __syncthreads();
    if (k0 + 32 < K) {
      sa0.ld(A  + (long)(m0 + r0) * K + k0 + 32 + cg);
      sa1.ld(A  + (long)(m0 + r1) * K + k0 + 32 + cg);
      sb0.ld(Bm + (long)(n0 + r0) * K + k0 + 32 + cg);
      sb1.ld(Bm + (long)(n0 + r1) * K + k0 + 32 + cg);
    }

    bf16x8 af[4], bfv[4];
#pragma unroll
    for (int i = 0; i < 4; i++)
      af[i] = *(const bf16x8*)&At[(wm * 64 + i * 16 + l16) * LAB + quad * 8];
#pragma unroll
    for (int j = 0; j < 4; j++)
      bfv[j] = *(const bf16x8*)&Bt[(wn * 64 + j * 16 + l16) * LAB + quad * 8];
#pragma unroll
    for (int i = 0; i < 4; i++)
#pragma unroll
      for (int j = 0; j < 4; j++)
        acc[i][j] = __builtin_amdgcn_mfma_f32_16x16x32_bf16(af[i], bfv[j], acc[i][j], 0, 0, 0);
  }

#pragma unroll
  for (int i = 0; i < 4; i++) {
    const int rbase = m0 + wm * 64 + i * 16 + quad * 4;
#pragma unroll
    for (int j = 0; j < 4; j++) {
      const int col = n0 + wn * 64 + j * 16 + l16;
      float bv = 0.f;
      if (MODE == 0) bv = bias[col];
#pragma unroll
      for (int r = 0; r < 4; r++) {
        const int row = rbase + r;
        float v = acc[i][j][r];
        if (MODE == 0) {
          ((float*)Cv)[(long)row * ND + col] = v + bv;
        } else if (MODE == 1) {
          int b = row >> 11, s = row & 2047, h = col >> 6, d = col & 63;
          ((u16t*)Cv)[(((long)(b * NH + h)) * NS + s) * NDK + d] = f2bf(v);
        } else {
          int b = row >> 11, s = row & 2047, h = col >> 6, d = col & 63;
          ((u16t*)Cv)[(((long)(b * NH + h)) * NDK + d) * NS + s] = f2bf(v);
        }
      }
    }
  }
}

// ---------------------------------------------------------------------------
// Flash attention pass: per (b,h, 128-row q tile). 4 waves x 32 q rows.
// exp2-domain online softmax, unconditional rescale (straight-line), DPP
// rotate-reduce (VALU pipe, short latency), swizzled [64][64] LDS tiles
// (conflict-free, verified), per-g P->LDS->PV round-trip (low reg pressure),
// software-pipelined K/V staging.
// (256,4): 16 waves/CU, VGPR cap 128 vs ~90 used. R2's spill disaster was the
// old high-pressure structure; the per-g form sits at 80 VGPR with headroom.
// Tripwire: WRITE_SIZE must stay ~17408 KB; any jump = spills -> revert.
// ---------------------------------------------------------------------------
__global__ __launch_bounds__(256, 4)
void flash_ctx(const u16t* __restrict__ Qw, const u16t* __restrict__ Kw,
               const u16t* __restrict__ VTw, const int* __restrict__ mask,
               u16t* __restrict__ ctx, float* __restrict__ mo, float* __restrict__ lo)
{
  __shared__ __attribute__((aligned(16))) u16t Kt[64 * 64];
  __shared__ __attribute__((aligned(16))) u16t Vt[64 * 64];
  __shared__ __attribute__((aligned(16))) u16t Pt[4 * 16 * 64];
  __shared__ float biasl[NS];

  const int tid  = threadIdx.x;
  const int w    = tid >> 6;
  const int lane = tid & 63;
  const int quad = lane >> 4;
  const int l16  = lane & 15;
  const int bh   = blockIdx.y;        // b*16 + h
  const int b    = bh >> 4;
  const int h    = bh & 15;
  const int qw   = blockIdx.x * 128 + w * 32;
  const int pbase = w * 1024;         // per-wave 16x64 P tile

  for (int i = tid; i < NS; i += 256)
    biasl[i] = mask[b * NS + i] ? 0.f : NEGINF;

  // preload this wave's Q fragments (32 rows x 64 d) into registers
  bf16x8 qf[2][2];
#pragma unroll
  for (int g = 0; g < 2; g++)
#pragma unroll
    for (int kk = 0; kk < 2; kk++)
      qf[g][kk] = *(const bf16x8*)(Qw + ((long)bh * NS + qw + g * 16 + l16) * NDK + kk * 32 + quad * 8);

  const f32x4 fz = {0.f, 0.f, 0.f, 0.f};
  const f32x4 fm = {NEGINF, NEGINF, NEGINF, NEGINF};
  f32x4 cacc[2][4];
#pragma unroll
  for (int g = 0; g < 2; g++)
#pragma unroll
    for (int d = 0; d < 4; d++) cacc[g][d] = fz;
  f32x4 mrun[2] = {fm, fm};
  f32x4 lrun[2] = {fz, fz};

  // staging chunk map: chunk c (0..511) -> row c>>3 (0..63), colgrp (c&7)*8
  const int kr0 = tid >> 3, kc0 = (tid & 7) * 8;
  const int kr1 = kr0 + 32;
  const long kbase = (long)bh * NS;
  const long vbase = (long)bh * NDK;

  bf16x8 k0v = *(const bf16x8*)(Kw  + (kbase + kr0) * NDK + kc0);
  bf16x8 k1v = *(const bf16x8*)(Kw  + (kbase + kr1) * NDK + kc0);
  bf16x8 v0v = *(const bf16x8*)(VTw + (vbase + kr0) * NS + kc0);
  bf16x8 v1v = *(const bf16x8*)(VTw + (vbase + kr1) * NS + kc0);

  for (int kb = 0; kb < NS; kb += 64) {
    __syncthreads();
    *(bf16x8*)&Kt[swz(kr0, kc0)] = k0v;
    *(bf16x8*)&Kt[swz(kr1, kc0)] = k1v;
    *(bf16x8*)&Vt[swz(kr0, kc0)] = v0v;
    *(bf16x8*)&Vt[swz(kr1, kc0)] = v1v;
    __syncthreads();
    if (kb + 64 < NS) {   // prefetch next tile; latency hides under compute
      k0v = *(const bf16x8*)(Kw  + (kbase + kb + 64 + kr0) * NDK + kc0);
      k1v = *(const bf16x8*)(Kw  + (kbase + kb + 64 + kr1) * NDK + kc0);
      v0v = *(const bf16x8*)(VTw + (vbase + kr0) * NS + kb + 64 + kc0);
      v1v = *(const bf16x8*)(VTw + (vbase + kr1) * NS + kb + 64 + kc0);
    }

    float bias_c[4];
#pragma unroll
    for (int c = 0; c < 4; c++) bias_c[c] = biasl[kb + c * 16 + l16];

#pragma unroll
    for (int g = 0; g < 2; g++) {
      // S = Q K^T (rows: q, cols: key) for this 16-row group
      f32x4 s[4];
#pragma unroll
      for (int c = 0; c < 4; c++) {
        f32x4 a = fz;
#pragma unroll
        for (int kk = 0; kk < 2; kk++) {
          bf16x8 kf = *(const bf16x8*)&Kt[swz(c * 16 + l16, kk * 32 + quad * 8)];
          a = __builtin_amdgcn_mfma_f32_16x16x32_bf16(qf[g][kk], kf, a, 0, 0, 0);
        }
        s[c] = a;
      }

#pragma unroll
      for (int c = 0; c < 4; c++)
#pragma unroll
        for (int r = 0; r < 4; r++)
          s[c][r] = s[c][r] * SCALE2 + bias_c[c];

      // row max across 4 col-frags then DPP rotate-reduce over the 16 lanes
      f32x4 mx = s[0];
#pragma unroll
      for (int c = 1; c < 4; c++)
#pragma unroll
        for (int r = 0; r < 4; r++) mx[r] = fmaxf(mx[r], s[c][r]);
#pragma unroll
      for (int r = 0; r < 4; r++) {
        float x = mx[r];
        x = fmaxf(x, ROR16(x, 1));
        x = fmaxf(x, ROR16(x, 2));
        x = fmaxf(x, ROR16(x, 4));
        x = fmaxf(x, ROR16(x, 8));
        mx[r] = x;
      }

      f32x4 alpha;
#pragma unroll
      for (int r = 0; r < 4; r++) {
        float mnew = fmaxf(mrun[g][r], mx[r]);
        alpha[r] = fexp2(mrun[g][r] - mnew);
        mrun[g][r] = mnew;
      }
#pragma unroll
      for (int c = 0; c < 4; c++)
#pragma unroll
        for (int r = 0; r < 4; r++) s[c][r] = fexp2(s[c][r] - mrun[g][r]);

      f32x4 sm = fz;
#pragma unroll
      for (int c = 0; c < 4; c++)
#pragma unroll
        for (int r = 0; r < 4; r++) sm[r] += s[c][r];
#pragma unroll
      for (int r = 0; r < 4; r++) {
        float x = sm[r];
        x += ROR16(x, 1);
        x += ROR16(x, 2);
        x += ROR16(x, 4);
        x += ROR16(x, 8);
        sm[r] = x;
      }
#pragma unroll
      for (int r = 0; r < 4; r++) lrun[g][r] = lrun[g][r] * alpha[r] + sm[r];
#pragma unroll
      for (int d = 0; d < 4; d++)
#pragma unroll
        for (int r = 0; r < 4; r++) cacc[g][d][r] *= alpha[r];

      // P(g) -> LDS (A-operand layout: [q][key] row-major, swizzled)
#pragma unroll
      for (int c = 0; c < 4; c++)
#pragma unroll
        for (int r = 0; r < 4; r++)
          Pt[pbase + swz(quad * 4 + r, c * 16 + l16)] = f2bf(s[c][r]);

      // context(g) += P(g) * V  (per-wave Pt; same-wave DS ops are in order)
#pragma unroll
      for (int d = 0; d < 4; d++)
#pragma unroll
        for (int kk = 0; kk < 2; kk++) {
          bf16x8 pf = *(const bf16x8*)&Pt[pbase + swz(l16, kk * 32 + quad * 8)];
          bf16x8 vf = *(const bf16x8*)&Vt[swz(d * 16 + l16, kk * 32 + quad * 8)];
          cacc[g][d] = __builtin_amdgcn_mfma_f32_16x16x32_bf16(pf, vf, cacc[g][d], 0, 0, 0);
        }
    }
  }

  // epilogue: normalize, write context and (m,l)
#pragma unroll
  for (int g = 0; g < 2; g++) {
    f32x4 rinv;
#pragma unroll
    for (int r = 0; r < 4; r++) rinv[r] = 1.f / lrun[g][r];
#pragma unroll
    for (int d = 0; d < 4; d++)
#pragma unroll
      for (int r = 0; r < 4; r++) {
        int qg = qw + g * 16 + quad * 4 + r;
        int e  = h * NDK + d * 16 + l16;
        ctx[((long)(b * NS + qg)) * ND + e] = f2bf(cacc[g][d][r] * rinv[r]);
      }
    if (l16 == 0) {
#pragma unroll
      for (int r = 0; r < 4; r++) {
        int qg = qw + g * 16 + quad * 4 + r;
        mo[(long)bh * NS + qg] = mrun[g][r];
        lo[(long)bh * NS + qg] = lrun[g][r];
      }
    }
  }
}

// ---------------------------------------------------------------------------
// probs_mean: per (b, 128x128 score tile), loop all 16 heads recomputing
// S = Q K^T, p = exp2(s*SCALE2 + maskbias - m)/l, accumulate mean, fp32 out.
// Swizzled [128][64] tiles (no pad); software-pipelined head staging.
// ---------------------------------------------------------------------------
__global__ __launch_bounds__(256, 3)
void probs_mean(const u16t* __restrict__ Qw, const u16t* __restrict__ Kw,
                const int* __restrict__ mask, const float* __restrict__ mo,
                const float* __restrict__ lo, float* __restrict__ outp)
{
  __shared__ __attribute__((aligned(16))) u16t Qt[128 * 64];
  __shared__ __attribute__((aligned(16))) u16t Kt2[128 * 64];
  __shared__ float ml[NH * 128];
  __shared__ float li[NH * 128];
  __shared__ float biasl[128];

  const int tid  = threadIdx.x;
  const int w    = tid >> 6;
  const int lane = tid & 63;
  const int quad = lane >> 4;
  const int l16  = lane & 15;
  const int wm   = w >> 1, wn = w & 1;
  const int b  = blockIdx.z;
  const int q0 = blockIdx.y * 128;
  const int k0 = blockIdx.x * 128;

  for (int i = tid; i < NH * 128; i += 256) {
    int hh = i >> 7, r = i & 127;
    ml[i] = mo[((long)(b * NH + hh)) * NS + q0 + r];
    li[i] = 1.f / lo[((long)(b * NH + hh)) * NS + q0 + r];
  }
  for (int i = tid; i < 128; i += 256)
    biasl[i] = mask[b * NS + k0 + i] ? 0.f : NEGINF;

  const f32x4 fz = {0.f, 0.f, 0.f, 0.f};
  f32x4 acc[4][4];
#pragma unroll
  for (int i = 0; i < 4; i++)
#pragma unroll
    for (int j = 0; j < 4; j++) acc[i][j] = fz;

  bf16x8 qv[4], kv[4];
#pragma unroll
  for (int rr = 0; rr < 4; rr++) {
    int idx = rr * 256 + tid;
    int row = idx >> 3, off = (idx & 7) * 8;
    qv[rr] = *(const bf16x8*)(Qw + ((long)(b * NH) * NS + q0 + row) * NDK + off);
    kv[rr] = *(const bf16x8*)(Kw + ((long)(b * NH) * NS + k0 + row) * NDK + off);
  }

  for (int hh = 0; hh < NH; hh++) {
    __syncthreads();
#pragma unroll
    for (int rr = 0; rr < 4; rr++) {
      int idx = rr * 256 + tid;
      int row = idx >> 3, off = (idx & 7) * 8;
      *(bf16x8*)&Qt[swz(row, off)]  = qv[rr];
      *(bf16x8*)&Kt2[swz(row, off)] = kv[rr];
    }
    __syncthreads();
    if (hh + 1 < NH) {
#pragma unroll
      for (int rr = 0; rr < 4; rr++) {
        int idx = rr * 256 + tid;
        int row = idx >> 3, off = (idx & 7) * 8;
        qv[rr] = *(const bf16x8*)(Qw + ((long)(b * NH + hh + 1) * NS + q0 + row) * NDK + off);
        kv[rr] = *(const bf16x8*)(Kw + ((long)(b * NH + hh + 1) * NS + k0 + row) * NDK + off);
      }
    }

    bf16x8 af[4][2], bfv[4][2];
#pragma unroll
    for (int i = 0; i < 4; i++)
#pragma unroll
      for (int kk = 0; kk < 2; kk++) {
        af[i][kk]  = *(const bf16x8*)&Qt[swz(wm * 64 + i * 16 + l16, kk * 32 + quad * 8)];
        bfv[i][kk] = *(const bf16x8*)&Kt2[swz(wn * 64 + i * 16 + l16, kk * 32 + quad * 8)];
      }
#pragma unroll
    for (int i = 0; i < 4; i++)
#pragma unroll
      for (int j = 0; j < 4; j++) {
        f32x4 s = fz;
#pragma unroll
        for (int kk = 0; kk < 2; kk++)
          s = __builtin_amdgcn_mfma_f32_16x16x32_bf16(af[i][kk], bfv[j][kk], s, 0, 0, 0);
        const float bias_c = biasl[wn * 64 + j * 16 + l16];
#pragma unroll
        for (int r = 0; r < 4; r++) {
          int rowb = wm * 64 + i * 16 + quad * 4 + r;
          float p = fexp2(s[r] * SCALE2 + bias_c - ml[hh * 128 + rowb]) * li[hh * 128 + rowb];
          acc[i][j][r] += p;
        }
      }
  }

#pragma unroll
  for (int i = 0; i < 4; i++)
#pragma unroll
    for (int j = 0; j < 4; j++)
#pragma unroll
      for (int r = 0; r < 4; r++) {
        int row = q0 + wm * 64 + i * 16 + quad * 4 + r;
        int col = k0 + wn * 64 + j * 16 + l16;
        outp[((long)(b * NS + row)) * NS + col] = acc[i][j][r] * (1.f / 16.f);
      }
}

// ---------------------------------------------------------------------------
extern "C" void kernel_launch(void* const* d_in, const int* in_sizes, int n_in,
                              void* d_out, int out_size, void* d_ws, size_t ws_size,
                              hipStream_t stream)
{
  (void)in_sizes; (void)n_in; (void)out_size; (void)ws_size;
  const float* query = (const float*)d_in[0];
  const float* keyt  = (const float*)d_in[1];
  const float* value = (const float*)d_in[2];
  const int*   mask  = (const int*)d_in[3];
  const float* Wq = (const float*)d_in[4];
  const float* Wk = (const float*)d_in[5];
  const float* Wv = (const float*)d_in[6];
  const float* Wo = (const float*)d_in[7];
  const float* bo = (const float*)d_in[8];

  float* out  = (float*)d_out;                     // [B,S,D] fp32
  float* outp = out + (long)NB * NS * ND;          // [B,S,S] fp32

  u16t* q_ws  = (u16t*)d_ws;                       // [B,H,S,dk] bf16
  u16t* k_ws  = q_ws + (long)NB * NH * NS * NDK;   // [B,H,S,dk] bf16
  u16t* vt_ws = k_ws + (long)NB * NH * NS * NDK;   // [B,H,dk,S] bf16
  float* m_ws = (float*)(vt_ws + (long)NB * NH * NS * NDK);
  float* l_ws = m_ws + (long)NB * NH * NS;
  // ctx scratch (bf16) lives in the outp region of d_out; it is fully
  // consumed by the output GEMM before probs_mean overwrites the region.
  u16t* ctx_ws = (u16t*)outp;

  dim3 blk(256);
  gemm_nt<float, 1><<<dim3(64, 8), blk, 0, stream>>>(query, Wq, q_ws, nullptr);
  gemm_nt<float, 1><<<dim3(64, 8), blk, 0, stream>>>(keyt,  Wk, k_ws, nullptr);
  gemm_nt<float, 2><<<dim3(64, 8), blk, 0, stream>>>(value, Wv, vt_ws, nullptr);
  flash_ctx<<<dim3(NS / 128, NB * NH), blk, 0, stream>>>(q_ws, k_ws, vt_ws, mask,
                                                         ctx_ws, m_ws, l_ws);
  gemm_nt<u16t, 0><<<dim3(64, 8), blk, 0, stream>>>(ctx_ws, Wo, out, bo);
  probs_mean<<<dim3(NS / 128, NS / 128, NB), blk, 0, stream>>>(q_ws, k_ws, mask,
                                                               m_ws, l_ws, outp);
}

// Round 6
// 518.324 us; speedup vs baseline: 1.6526x; 1.1171x over previous
//
#include <hip/hip_runtime.h>

typedef unsigned short u16t;
typedef __bf16 bf16x8 __attribute__((ext_vector_type(8)));
typedef float f32x4 __attribute__((ext_vector_type(4)));

#define NB 4
#define NS 2048
#define ND 1024
#define NH 16
#define NDK 64
#define NEGINF -1.0e9f
// softmax runs in exp2 domain: SCALE2 = 0.125 * log2(e)
#define SCALE2 0.18033688011112042f

// padded LDS row stride for gemm (32-wide tiles): 40 elem = 80B, 5 granules,
// coprime with 8 -> conflict-free frag reads.
#define LAB 40

__device__ __forceinline__ float fexp2(float x) { return __builtin_amdgcn_exp2f(x); }

// native bf16 convert (RNE via v_cvt_pk_bf16_f32; 1 inst vs 3 bit-ops)
__device__ __forceinline__ u16t f2bf(float f) {
  return __builtin_bit_cast(u16t, (__bf16)f);
}

// DPP rotate within 16-lane rows (softmax reduce: VALU pipe, ~3 cyc/step vs
// ~35 cyc ds_bpermute for shfl). Correctness verified R2/R5.
#define ROR16(x, n) __builtin_bit_cast(float, __builtin_amdgcn_update_dpp(     \
    __builtin_bit_cast(int, (x)), __builtin_bit_cast(int, (x)),                \
    0x120 + (n), 0xF, 0xF, false))

// XOR-swizzle index for [*][64] u16 tiles: rotates 16B granules within each
// 8-row stripe -> conflict-free b128 reads at 128B row stride (no padding).
// Verified: SQ_LDS_BANK_CONFLICT == 0 since R2.
__device__ __forceinline__ int swz(int row, int col) {
  return row * 64 + (col ^ ((row & 7) << 3));
}

// register staging helpers (raw loads now, convert at LDS-store time)
template<typename TA> struct Stg;
template<> struct Stg<float> {
  f32x4 lo, hi;
  __device__ __forceinline__ void ld(const float* p) {
    lo = *(const f32x4*)p; hi = *(const f32x4*)(p + 4);
  }
  __device__ __forceinline__ bf16x8 get() const {
    bf16x8 r;
    r[0] = (__bf16)lo[0]; r[1] = (__bf16)lo[1]; r[2] = (__bf16)lo[2]; r[3] = (__bf16)lo[3];
    r[4] = (__bf16)hi[0]; r[5] = (__bf16)hi[1]; r[6] = (__bf16)hi[2]; r[7] = (__bf16)hi[3];
    return r;
  }
};
template<> struct Stg<u16t> {
  bf16x8 v;
  __device__ __forceinline__ void ld(const u16t* p) { v = *(const bf16x8*)p; }
  __device__ __forceinline__ bf16x8 get() const { return v; }
};

// ---------------------------------------------------------------------------
// NT GEMM: C[M,N] = A[M,K] * B[N,K]^T ; M=8192, N=K=1024, bf16 MFMA, fp32 acc.
// MODE 0: C fp32 row-major [M,N] + bias[col]   (output projection -> d_out)
// MODE 1: C bf16 scatter to [B,H,S,dk]         (Q/K projections -> ws)
// MODE 2: C bf16 scatter to [B,H,dk,S]         (V projection, transposed -> ws)
// Software-pipelined: next K-step's global loads issue before the MFMA block.
// ---------------------------------------------------------------------------
template<typename TA, int MODE>
__global__ __launch_bounds__(256, 2)
void gemm_nt(const TA* __restrict__ A, const float* __restrict__ Bm,
             void* __restrict__ Cv, const float* __restrict__ bias)
{
  const int K = 1024;
  __shared__ __attribute__((aligned(16))) u16t At[128 * LAB];
  __shared__ __attribute__((aligned(16))) u16t Bt[128 * LAB];

  const int tid  = threadIdx.x;
  const int w    = tid >> 6;
  const int lane = tid & 63;
  const int quad = lane >> 4;
  const int l16  = lane & 15;
  const int wm   = w >> 1, wn = w & 1;
  const int m0   = blockIdx.x * 128;
  const int n0   = blockIdx.y * 128;

  const f32x4 fz = {0.f, 0.f, 0.f, 0.f};
  f32x4 acc[4][4];
#pragma unroll
  for (int i = 0; i < 4; i++)
#pragma unroll
    for (int j = 0; j < 4; j++) acc[i][j] = fz;

  // staging chunk map: chunk c (0..511) -> row c>>2 (0..127), colgrp (c&3)*8
  const int r0 = tid >> 2, cg = (tid & 3) * 8;
  const int r1 = r0 + 64;

  Stg<TA> sa0, sa1; Stg<float> sb0, sb1;
  sa0.ld(A  + (long)(m0 + r0) * K + cg);
  sa1.ld(A  + (long)(m0 + r1) * K + cg);
  sb0.ld(Bm + (long)(n0 + r0) * K + cg);
  sb1.ld(Bm + (long)(n0 + r1) * K + cg);

  for (int k0 = 0; k0 < K; k0 += 32) {
    __syncthreads();
    *(bf16x8*)&At[r0 * LAB + cg] = sa0.get();
    *(bf16x8*)&At[r1 * LAB + cg] = sa1.get();
    *(bf16x8*)&Bt[r0 * LAB + cg] = sb0.get();
    *(bf16x8*)&Bt[r1 * LAB + cg] = sb1.get();
    __syncthreads();
    if (k0 + 32 < K) {
      sa0.ld(A  + (long)(m0 + r0) * K + k0 + 32 + cg);
      sa1.ld(A  + (long)(m0 + r1) * K + k0 + 32 + cg);
      sb0.ld(Bm + (long)(n0 + r0) * K + k0 + 32 + cg);
      sb1.ld(Bm + (long)(n0 + r1) * K + k0 + 32 + cg);
    }

    bf16x8 af[4], bfv[4];
#pragma unroll
    for (int i = 0; i < 4; i++)
      af[i] = *(const bf16x8*)&At[(wm * 64 + i * 16 + l16) * LAB + quad * 8];
#pragma unroll
    for (int j = 0; j < 4; j++)
      bfv[j] = *(const bf16x8*)&Bt[(wn * 64 + j * 16 + l16) * LAB + quad * 8];
#pragma unroll
    for (int i = 0; i < 4; i++)
#pragma unroll
      for (int j = 0; j < 4; j++)
        acc[i][j] = __builtin_amdgcn_mfma_f32_16x16x32_bf16(af[i], bfv[j], acc[i][j], 0, 0, 0);
  }

#pragma unroll
  for (int i = 0; i < 4; i++) {
    const int rbase = m0 + wm * 64 + i * 16 + quad * 4;
#pragma unroll
    for (int j = 0; j < 4; j++) {
      const int col = n0 + wn * 64 + j * 16 + l16;
      float bv = 0.f;
      if (MODE == 0) bv = bias[col];
#pragma unroll
      for (int r = 0; r < 4; r++) {
        const int row = rbase + r;
        float v = acc[i][j][r];
        if (MODE == 0) {
          ((float*)Cv)[(long)row * ND + col] = v + bv;
        } else if (MODE == 1) {
          int b = row >> 11, s = row & 2047, h = col >> 6, d = col & 63;
          ((u16t*)Cv)[(((long)(b * NH + h)) * NS + s) * NDK + d] = f2bf(v);
        } else {
          int b = row >> 11, s = row & 2047, h = col >> 6, d = col & 63;
          ((u16t*)Cv)[(((long)(b * NH + h)) * NDK + d) * NS + s] = f2bf(v);
        }
      }
    }
  }
}

// ---------------------------------------------------------------------------
// Flash attention pass: per (b,h, 128-row q tile). 8 waves x 16 q rows
// (512-thread blocks): the g-dimension of R4/R5 is folded into wave count,
// halving per-wave register state (qf 8, cacc 16, mrun/lrun 8, prefetch 8)
// so 16 waves/CU fit WITHOUT spills (R5: (256,4) spilled 460 MB/dispatch).
// exp2-domain online softmax, DPP rotate-reduce, swizzled conflict-free LDS,
// software-pipelined K/V staging (1 K + 1 V load per thread).
// Tripwire: WRITE_SIZE must stay ~17408 KB; any jump = spills -> revert.
// ---------------------------------------------------------------------------
__global__ __launch_bounds__(512, 4)
void flash_ctx(const u16t* __restrict__ Qw, const u16t* __restrict__ Kw,
               const u16t* __restrict__ VTw, const int* __restrict__ mask,
               u16t* __restrict__ ctx, float* __restrict__ mo, float* __restrict__ lo)
{
  __shared__ __attribute__((aligned(16))) u16t Kt[64 * 64];
  __shared__ __attribute__((aligned(16))) u16t Vt[64 * 64];
  __shared__ __attribute__((aligned(16))) u16t Pt[8 * 16 * 64];
  __shared__ float biasl[NS];

  const int tid  = threadIdx.x;
  const int w    = tid >> 6;
  const int lane = tid & 63;
  const int quad = lane >> 4;
  const int l16  = lane & 15;
  const int bh   = blockIdx.y;        // b*16 + h
  const int b    = bh >> 4;
  const int h    = bh & 15;
  const int qw   = blockIdx.x * 128 + w * 16;
  const int pbase = w * 1024;         // per-wave 16x64 P tile

  for (int i = tid; i < NS; i += 512)
    biasl[i] = mask[b * NS + i] ? 0.f : NEGINF;

  // preload this wave's Q fragments (16 rows x 64 d) into registers
  bf16x8 qf[2];
#pragma unroll
  for (int kk = 0; kk < 2; kk++)
    qf[kk] = *(const bf16x8*)(Qw + ((long)bh * NS + qw + l16) * NDK + kk * 32 + quad * 8);

  const f32x4 fz = {0.f, 0.f, 0.f, 0.f};
  const f32x4 fm = {NEGINF, NEGINF, NEGINF, NEGINF};
  f32x4 cacc[4];
#pragma unroll
  for (int d = 0; d < 4; d++) cacc[d] = fz;
  f32x4 mrun = fm;
  f32x4 lrun = fz;

  // staging chunk map: chunk c (0..511) -> row c>>3 (0..63), colgrp (c&7)*8
  const int kr0 = tid >> 3, kc0 = (tid & 7) * 8;
  const long kbase = (long)bh * NS;
  const long vbase = (long)bh * NDK;

  bf16x8 kv = *(const bf16x8*)(Kw  + (kbase + kr0) * NDK + kc0);
  bf16x8 vv = *(const bf16x8*)(VTw + (vbase + kr0) * NS + kc0);

  for (int kb = 0; kb < NS; kb += 64) {
    __syncthreads();
    *(bf16x8*)&Kt[swz(kr0, kc0)] = kv;
    *(bf16x8*)&Vt[swz(kr0, kc0)] = vv;
    __syncthreads();
    if (kb + 64 < NS) {   // prefetch next tile; latency hides under compute
      kv = *(const bf16x8*)(Kw  + (kbase + kb + 64 + kr0) * NDK + kc0);
      vv = *(const bf16x8*)(VTw + (vbase + kr0) * NS + kb + 64 + kc0);
    }

    // S = Q K^T (rows: q, cols: key) for this wave's 16 rows
    f32x4 s[4];
#pragma unroll
    for (int c = 0; c < 4; c++) {
      f32x4 a = fz;
#pragma unroll
      for (int kk = 0; kk < 2; kk++) {
        bf16x8 kf = *(const bf16x8*)&Kt[swz(c * 16 + l16, kk * 32 + quad * 8)];
        a = __builtin_amdgcn_mfma_f32_16x16x32_bf16(qf[kk], kf, a, 0, 0, 0);
      }
      s[c] = a;
    }

#pragma unroll
    for (int c = 0; c < 4; c++) {
      const float bias_c = biasl[kb + c * 16 + l16];
#pragma unroll
      for (int r = 0; r < 4; r++)
        s[c][r] = s[c][r] * SCALE2 + bias_c;
    }

    // row max across 4 col-frags then DPP rotate-reduce over the 16 lanes
    f32x4 mx = s[0];
#pragma unroll
    for (int c = 1; c < 4; c++)
#pragma unroll
      for (int r = 0; r < 4; r++) mx[r] = fmaxf(mx[r], s[c][r]);
#pragma unroll
    for (int r = 0; r < 4; r++) {
      float x = mx[r];
      x = fmaxf(x, ROR16(x, 1));
      x = fmaxf(x, ROR16(x, 2));
      x = fmaxf(x, ROR16(x, 4));
      x = fmaxf(x, ROR16(x, 8));
      mx[r] = x;
    }

    f32x4 alpha;
#pragma unroll
    for (int r = 0; r < 4; r++) {
      float mnew = fmaxf(mrun[r], mx[r]);
      alpha[r] = fexp2(mrun[r] - mnew);
      mrun[r] = mnew;
    }
#pragma unroll
    for (int c = 0; c < 4; c++)
#pragma unroll
      for (int r = 0; r < 4; r++) s[c][r] = fexp2(s[c][r] - mrun[r]);

    f32x4 sm = fz;
#pragma unroll
    for (int c = 0; c < 4; c++)
#pragma unroll
      for (int r = 0; r < 4; r++) sm[r] += s[c][r];
#pragma unroll
    for (int r = 0; r < 4; r++) {
      float x = sm[r];
      x += ROR16(x, 1);
      x += ROR16(x, 2);
      x += ROR16(x, 4);
      x += ROR16(x, 8);
      sm[r] = x;
    }
#pragma unroll
    for (int r = 0; r < 4; r++) lrun[r] = lrun[r] * alpha[r] + sm[r];
#pragma unroll
    for (int d = 0; d < 4; d++)
#pragma unroll
      for (int r = 0; r < 4; r++) cacc[d][r] *= alpha[r];

    // P -> LDS (A-operand layout: [q][key] row-major, swizzled)
#pragma unroll
    for (int c = 0; c < 4; c++)
#pragma unroll
      for (int r = 0; r < 4; r++)
        Pt[pbase + swz(quad * 4 + r, c * 16 + l16)] = f2bf(s[c][r]);

    // context += P * V  (per-wave Pt; same-wave DS ops are in order)
#pragma unroll
    for (int d = 0; d < 4; d++)
#pragma unroll
      for (int kk = 0; kk < 2; kk++) {
        bf16x8 pf = *(const bf16x8*)&Pt[pbase + swz(l16, kk * 32 + quad * 8)];
        bf16x8 vf = *(const bf16x8*)&Vt[swz(d * 16 + l16, kk * 32 + quad * 8)];
        cacc[d] = __builtin_amdgcn_mfma_f32_16x16x32_bf16(pf, vf, cacc[d], 0, 0, 0);
      }
  }

  // epilogue: normalize, write context and (m,l)
  {
    f32x4 rinv;
#pragma unroll
    for (int r = 0; r < 4; r++) rinv[r] = 1.f / lrun[r];
#pragma unroll
    for (int d = 0; d < 4; d++)
#pragma unroll
      for (int r = 0; r < 4; r++) {
        int qg = qw + quad * 4 + r;
        int e  = h * NDK + d * 16 + l16;
        ctx[((long)(b * NS + qg)) * ND + e] = f2bf(cacc[d][r] * rinv[r]);
      }
    if (l16 == 0) {
#pragma unroll
      for (int r = 0; r < 4; r++) {
        int qg = qw + quad * 4 + r;
        mo[(long)bh * NS + qg] = mrun[r];
        lo[(long)bh * NS + qg] = lrun[r];
      }
    }
  }
}

// ---------------------------------------------------------------------------
// probs_mean: per (b, 128x128 score tile), loop all 16 heads recomputing
// S = Q K^T, p = exp2(s*SCALE2 + maskbias - m)/l, accumulate mean, fp32 out.
// Swizzled [128][64] tiles (no pad); software-pipelined head staging.
// ---------------------------------------------------------------------------
__global__ __launch_bounds__(256, 3)
void probs_mean(const u16t* __restrict__ Qw, const u16t* __restrict__ Kw,
                const int* __restrict__ mask, const float* __restrict__ mo,
                const float* __restrict__ lo, float* __restrict__ outp)
{
  __shared__ __attribute__((aligned(16))) u16t Qt[128 * 64];
  __shared__ __attribute__((aligned(16))) u16t Kt2[128 * 64];
  __shared__ float ml[NH * 128];
  __shared__ float li[NH * 128];
  __shared__ float biasl[128];

  const int tid  = threadIdx.x;
  const int w    = tid >> 6;
  const int lane = tid & 63;
  const int quad = lane >> 4;
  const int l16  = lane & 15;
  const int wm   = w >> 1, wn = w & 1;
  const int b  = blockIdx.z;
  const int q0 = blockIdx.y * 128;
  const int k0 = blockIdx.x * 128;

  for (int i = tid; i < NH * 128; i += 256) {
    int hh = i >> 7, r = i & 127;
    ml[i] = mo[((long)(b * NH + hh)) * NS + q0 + r];
    li[i] = 1.f / lo[((long)(b * NH + hh)) * NS + q0 + r];
  }
  for (int i = tid; i < 128; i += 256)
    biasl[i] = mask[b * NS + k0 + i] ? 0.f : NEGINF;

  const f32x4 fz = {0.f, 0.f, 0.f, 0.f};
  f32x4 acc[4][4];
#pragma unroll
  for (int i = 0; i < 4; i++)
#pragma unroll
    for (int j = 0; j < 4; j++) acc[i][j] = fz;

  bf16x8 qv[4], kv[4];
#pragma unroll
  for (int rr = 0; rr < 4; rr++) {
    int idx = rr * 256 + tid;
    int row = idx >> 3, off = (idx & 7) * 8;
    qv[rr] = *(const bf16x8*)(Qw + ((long)(b * NH) * NS + q0 + row) * NDK + off);
    kv[rr] = *(const bf16x8*)(Kw + ((long)(b * NH) * NS + k0 + row) * NDK + off);
  }

  for (int hh = 0; hh < NH; hh++) {
    __syncthreads();
#pragma unroll
    for (int rr = 0; rr < 4; rr++) {
      int idx = rr * 256 + tid;
      int row = idx >> 3, off = (idx & 7) * 8;
      *(bf16x8*)&Qt[swz(row, off)]  = qv[rr];
      *(bf16x8*)&Kt2[swz(row, off)] = kv[rr];
    }
    __syncthreads();
    if (hh + 1 < NH) {
#pragma unroll
      for (int rr = 0; rr < 4; rr++) {
        int idx = rr * 256 + tid;
        int row = idx >> 3, off = (idx & 7) * 8;
        qv[rr] = *(const bf16x8*)(Qw + ((long)(b * NH + hh + 1) * NS + q0 + row) * NDK + off);
        kv[rr] = *(const bf16x8*)(Kw + ((long)(b * NH + hh + 1) * NS + k0 + row) * NDK + off);
      }
    }

    bf16x8 af[4][2], bfv[4][2];
#pragma unroll
    for (int i = 0; i < 4; i++)
#pragma unroll
      for (int kk = 0; kk < 2; kk++) {
        af[i][kk]  = *(const bf16x8*)&Qt[swz(wm * 64 + i * 16 + l16, kk * 32 + quad * 8)];
        bfv[i][kk] = *(const bf16x8*)&Kt2[swz(wn * 64 + i * 16 + l16, kk * 32 + quad * 8)];
      }
#pragma unroll
    for (int i = 0; i < 4; i++)
#pragma unroll
      for (int j = 0; j < 4; j++) {
        f32x4 s = fz;
#pragma unroll
        for (int kk = 0; kk < 2; kk++)
          s = __builtin_amdgcn_mfma_f32_16x16x32_bf16(af[i][kk], bfv[j][kk], s, 0, 0, 0);
        const float bias_c = biasl[wn * 64 + j * 16 + l16];
#pragma unroll
        for (int r = 0; r < 4; r++) {
          int rowb = wm * 64 + i * 16 + quad * 4 + r;
          float p = fexp2(s[r] * SCALE2 + bias_c - ml[hh * 128 + rowb]) * li[hh * 128 + rowb];
          acc[i][j][r] += p;
        }
      }
  }

#pragma unroll
  for (int i = 0; i < 4; i++)
#pragma unroll
    for (int j = 0; j < 4; j++)
#pragma unroll
      for (int r = 0; r < 4; r++) {
        int row = q0 + wm * 64 + i * 16 + quad * 4 + r;
        int col = k0 + wn * 64 + j * 16 + l16;
        outp[((long)(b * NS + row)) * NS + col] = acc[i][j][r] * (1.f / 16.f);
      }
}

// ---------------------------------------------------------------------------
extern "C" void kernel_launch(void* const* d_in, const int* in_sizes, int n_in,
                              void* d_out, int out_size, void* d_ws, size_t ws_size,
                              hipStream_t stream)
{
  (void)in_sizes; (void)n_in; (void)out_size; (void)ws_size;
  const float* query = (const float*)d_in[0];
  const float* keyt  = (const float*)d_in[1];
  const float* value = (const float*)d_in[2];
  const int*   mask  = (const int*)d_in[3];
  const float* Wq = (const float*)d_in[4];
  const float* Wk = (const float*)d_in[5];
  const float* Wv = (const float*)d_in[6];
  const float* Wo = (const float*)d_in[7];
  const float* bo = (const float*)d_in[8];

  float* out  = (float*)d_out;                     // [B,S,D] fp32
  float* outp = out + (long)NB * NS * ND;          // [B,S,S] fp32

  u16t* q_ws  = (u16t*)d_ws;                       // [B,H,S,dk] bf16
  u16t* k_ws  = q_ws + (long)NB * NH * NS * NDK;   // [B,H,S,dk] bf16
  u16t* vt_ws = k_ws + (long)NB * NH * NS * NDK;   // [B,H,dk,S] bf16
  float* m_ws = (float*)(vt_ws + (long)NB * NH * NS * NDK);
  float* l_ws = m_ws + (long)NB * NH * NS;
  // ctx scratch (bf16) lives in the outp region of d_out; it is fully
  // consumed by the output GEMM before probs_mean overwrites the region.
  u16t* ctx_ws = (u16t*)outp;

  dim3 blk(256);
  gemm_nt<float, 1><<<dim3(64, 8), blk, 0, stream>>>(query, Wq, q_ws, nullptr);
  gemm_nt<float, 1><<<dim3(64, 8), blk, 0, stream>>>(keyt,  Wk, k_ws, nullptr);
  gemm_nt<float, 2><<<dim3(64, 8), blk, 0, stream>>>(value, Wv, vt_ws, nullptr);
  flash_ctx<<<dim3(NS / 128, NB * NH), dim3(512), 0, stream>>>(q_ws, k_ws, vt_ws, mask,
                                                               ctx_ws, m_ws, l_ws);
  gemm_nt<u16t, 0><<<dim3(64, 8), blk, 0, stream>>>(ctx_ws, Wo, out, bo);
  probs_mean<<<dim3(NS / 128, NS / 128, NB), blk, 0, stream>>>(q_ws, k_ws, mask,
                                                               m_ws, l_ws, outp);
}